// Round 1
// baseline (368.412 us; speedup 1.0000x reference)
//
#include <hip/hip_runtime.h>
#include <stdint.h>

// _TransformerBlockQuantum on MI355X (gfx950).
// Pipeline: cast->bf16 | fused QKV MFMA GEMM | V transpose | flash attention (MFMA)
//           | Wo MFMA GEMM | add+LN1 | per-token 8-qubit sim + Wout + ReLU + add + LN2.

typedef unsigned short u16;
typedef unsigned int   u32;
typedef __bf16 bf16x8 __attribute__((ext_vector_type(8)));
typedef u16    u16x8  __attribute__((ext_vector_type(8)));
typedef float  f32x4  __attribute__((ext_vector_type(4)));

#define DEV static __device__ __forceinline__

DEV u16 f2b(float f){ u32 u = __float_as_uint(f); return (u16)((u + 0x7fffu + ((u>>16)&1u)) >> 16); }

#define MFMA16(a,b,c) __builtin_amdgcn_mfma_f32_16x16x32_bf16((a),(b),(c),0,0,0)
#define GLD16(gp,lp) __builtin_amdgcn_global_load_lds( \
    (const __attribute__((address_space(1))) u32*)(const void*)(gp), \
    (__attribute__((address_space(3))) u32*)(void*)(lp), 16, 0, 0)

// ---------------- cast f32 -> bf16, 8 elems/thread ----------------
__global__ __launch_bounds__(256) void k_cast(const float* __restrict__ src, u16* __restrict__ dst){
  const int i = blockIdx.x*256 + threadIdx.x;
  const f32x4* s = (const f32x4*)src + (size_t)i*2;
  f32x4 a = s[0], b = s[1];
  u16x8 o;
  o[0]=f2b(a.x); o[1]=f2b(a.y); o[2]=f2b(a.z); o[3]=f2b(a.w);
  o[4]=f2b(b.x); o[5]=f2b(b.y); o[6]=f2b(b.z); o[7]=f2b(b.w);
  ((u16x8*)dst)[i] = o;
}

// ---------------- C = A * B^T  (A:[M,K] bf16, B:[N,K] bf16) ----------------
// MODE 0: N=3072 fused QKV epilogue -> bf16 q(*0.125)/k/v buffers [4096][1024]
// MODE 1: f32 epilogue into Cf[M][N]
template<int MODE>
__global__ __launch_bounds__(256) void k_gemm_nt(
    const u16* __restrict__ A, const u16* __restrict__ B,
    float* __restrict__ Cf, u16* __restrict__ Qo, u16* __restrict__ Ko, u16* __restrict__ Vo,
    int K, int N)
{
  __shared__ __attribute__((aligned(16))) u16 As[128*64];
  __shared__ __attribute__((aligned(16))) u16 Bs[128*64];
  const int tid = threadIdx.x, lane = tid & 63, w = tid >> 6;
  const int wr = w >> 1, wc = w & 1;
  const int m0 = blockIdx.y*128, n0 = blockIdx.x*128;
  const int l15 = lane & 15, lg = lane >> 4;
  f32x4 acc[4][4] = {};
  const int lr = lane >> 3, lc = (lane & 7)*8;
  const u16* ag = A + (size_t)(m0 + w*32 + lr)*K + lc;
  const u16* bg = B + (size_t)(n0 + w*32 + lr)*K + lc;
  u16* asl = &As[(w*32)*64];
  u16* bsl = &Bs[(w*32)*64];
  for (int k0 = 0; k0 < K; k0 += 64){
    __syncthreads();
    #pragma unroll
    for (int c = 0; c < 4; ++c){
      GLD16(ag + (size_t)(c*8)*K + k0, asl + c*512);
      GLD16(bg + (size_t)(c*8)*K + k0, bsl + c*512);
    }
    __syncthreads();
    #pragma unroll
    for (int kk = 0; kk < 2; ++kk){
      const int ko = kk*32 + lg*8;
      bf16x8 af[4], bf[4];
      #pragma unroll
      for (int t=0;t<4;++t) af[t] = *(const bf16x8*)&As[(wr*64 + t*16 + l15)*64 + ko];
      #pragma unroll
      for (int t=0;t<4;++t) bf[t] = *(const bf16x8*)&Bs[(wc*64 + t*16 + l15)*64 + ko];
      #pragma unroll
      for (int i=0;i<4;++i)
        #pragma unroll
        for (int j=0;j<4;++j)
          acc[i][j] = MFMA16(af[i], bf[j], acc[i][j]);
    }
  }
  const int col0 = n0 + wc*64 + l15;
  const int row0 = m0 + wr*64 + lg*4;
  #pragma unroll
  for (int i=0;i<4;++i)
  #pragma unroll
  for (int j=0;j<4;++j){
    const int cc = col0 + j*16;
    #pragma unroll
    for (int r=0;r<4;++r){
      const int rr = row0 + i*16 + r;
      const float v = acc[i][j][r];
      if (MODE==0){
        const int which = cc >> 10, c2 = cc & 1023;
        u16* dst = (which==0) ? Qo : ((which==1) ? Ko : Vo);
        dst[(size_t)rr*1024 + c2] = f2b(which==0 ? v*0.125f : v);
      } else {
        Cf[(size_t)rr*N + cc] = v;
      }
    }
  }
}

// ---------------- v[4096][1024] -> vt[(b*16+h)][d:64][s:2048] ----------------
__global__ __launch_bounds__(256) void k_transpose_v(const u16* __restrict__ v, u16* __restrict__ vt){
  __shared__ __attribute__((aligned(16))) u16 t[64*72];
  const int p = blockIdx.x >> 5, st = blockIdx.x & 31;
  const int b = p >> 4, h = p & 15;
  const int s0 = st*64;
  const int r = threadIdx.x >> 2, c = (threadIdx.x & 3)*16;
  const u16* src = v + (size_t)(b*2048 + s0 + r)*1024 + h*64 + c;
  *(uint4*)&t[r*72 + c]     = *(const uint4*)src;
  *(uint4*)&t[r*72 + c + 8] = *(const uint4*)(src + 8);
  __syncthreads();
  u16x8 o0, o1;
  #pragma unroll
  for (int j=0;j<8;++j){ o0[j] = t[(c+j)*72 + r]; o1[j] = t[(c+8+j)*72 + r]; }
  u16* dst = vt + ((size_t)p*64 + r)*2048 + s0 + c;
  *(u16x8*)dst       = o0;
  *(u16x8*)(dst + 8) = o1;
}

// ---------------- flash attention; q pre-scaled by 1/8 ----------------
__global__ __launch_bounds__(256) void k_attn(
    const u16* __restrict__ q, const u16* __restrict__ k,
    const u16* __restrict__ vt, u16* __restrict__ o)
{
  __shared__ __attribute__((aligned(16))) u16 Ks[64*72];
  __shared__ __attribute__((aligned(16))) u16 Vs[64*72];
  __shared__ __attribute__((aligned(16))) u16 Ps[4][32*72];
  const int tid = threadIdx.x, lane = tid & 63, w = tid >> 6;
  const int p = blockIdx.x >> 4, qt = blockIdx.x & 15;
  const int b = p >> 4, h = p & 15;
  const int t0 = b*2048 + qt*128 + w*32;
  const int l15 = lane & 15, lg = lane >> 4;
  bf16x8 qa[2][2];
  #pragma unroll
  for (int mt=0;mt<2;++mt)
  #pragma unroll
  for (int kk=0;kk<2;++kk)
    qa[mt][kk] = *(const bf16x8*)(q + (size_t)(t0 + mt*16 + l15)*1024 + h*64 + kk*32 + lg*8);
  f32x4 oacc[2][4] = {};
  float mrow[2][4], lrow[2][4];
  #pragma unroll
  for (int i=0;i<2;++i)
  #pragma unroll
  for (int r=0;r<4;++r){ mrow[i][r] = -1e30f; lrow[i][r] = 0.f; }
  const int sr = tid >> 2, sc = (tid & 3)*16;
  const u16* kg = k + (size_t)(b*2048 + sr)*1024 + h*64 + sc;
  const u16* vg = vt + ((size_t)p*64 + sr)*2048 + sc;
  for (int kv0 = 0; kv0 < 2048; kv0 += 64){
    __syncthreads();
    {
      const u16* s1 = kg + (size_t)kv0*1024;
      *(uint4*)&Ks[sr*72 + sc]     = *(const uint4*)s1;
      *(uint4*)&Ks[sr*72 + sc + 8] = *(const uint4*)(s1 + 8);
      const u16* s2 = vg + kv0;
      *(uint4*)&Vs[sr*72 + sc]     = *(const uint4*)s2;
      *(uint4*)&Vs[sr*72 + sc + 8] = *(const uint4*)(s2 + 8);
    }
    __syncthreads();
    f32x4 sacc[2][4] = {};
    #pragma unroll
    for (int kk=0;kk<2;++kk){
      const int ko = kk*32 + lg*8;
      bf16x8 kb[4];
      #pragma unroll
      for (int nt=0;nt<4;++nt) kb[nt] = *(const bf16x8*)&Ks[(nt*16 + l15)*72 + ko];
      #pragma unroll
      for (int mt=0;mt<2;++mt)
      #pragma unroll
      for (int nt=0;nt<4;++nt)
        sacc[mt][nt] = MFMA16(qa[mt][kk], kb[nt], sacc[mt][nt]);
    }
    #pragma unroll
    for (int mt=0;mt<2;++mt)
    #pragma unroll
    for (int r=0;r<4;++r){
      float mx = fmaxf(fmaxf(sacc[mt][0][r], sacc[mt][1][r]), fmaxf(sacc[mt][2][r], sacc[mt][3][r]));
      #pragma unroll
      for (int off=1; off<16; off<<=1) mx = fmaxf(mx, __shfl_xor(mx, off));
      const float mnew = fmaxf(mrow[mt][r], mx);
      const float scl = __expf(mrow[mt][r] - mnew);
      mrow[mt][r] = mnew;
      float rsum = 0.f;
      #pragma unroll
      for (int nt=0;nt<4;++nt){ float e = __expf(sacc[mt][nt][r] - mnew); sacc[mt][nt][r] = e; rsum += e; }
      #pragma unroll
      for (int off=1; off<16; off<<=1) rsum += __shfl_xor(rsum, off);
      lrow[mt][r] = lrow[mt][r]*scl + rsum;
      #pragma unroll
      for (int nt=0;nt<4;++nt) oacc[mt][nt][r] *= scl;
    }
    #pragma unroll
    for (int mt=0;mt<2;++mt)
    #pragma unroll
    for (int nt=0;nt<4;++nt)
    #pragma unroll
    for (int r=0;r<4;++r)
      Ps[w][(mt*16 + lg*4 + r)*72 + nt*16 + l15] = f2b(sacc[mt][nt][r]);
    #pragma unroll
    for (int kk=0;kk<2;++kk){
      const int ko = kk*32 + lg*8;
      bf16x8 pf[2], vf[4];
      #pragma unroll
      for (int mt=0;mt<2;++mt) pf[mt] = *(const bf16x8*)&Ps[w][(mt*16 + l15)*72 + ko];
      #pragma unroll
      for (int nt=0;nt<4;++nt) vf[nt] = *(const bf16x8*)&Vs[(nt*16 + l15)*72 + ko];
      #pragma unroll
      for (int mt=0;mt<2;++mt)
      #pragma unroll
      for (int nt=0;nt<4;++nt)
        oacc[mt][nt] = MFMA16(pf[mt], vf[nt], oacc[mt][nt]);
    }
  }
  #pragma unroll
  for (int mt=0;mt<2;++mt)
  #pragma unroll
  for (int nt=0;nt<4;++nt)
  #pragma unroll
  for (int r=0;r<4;++r){
    const int rr = t0 + mt*16 + lg*4 + r;
    const int cc = h*64 + nt*16 + l15;
    o[(size_t)rr*1024 + cc] = f2b(oacc[mt][nt][r] / lrow[mt][r]);
  }
}

// ---------------- out = LN(x + a) * g + b ----------------
__global__ __launch_bounds__(256) void k_add_ln(
    const float* __restrict__ x, const float* __restrict__ a,
    const float* __restrict__ g, const float* __restrict__ bb,
    float* __restrict__ out)
{
  __shared__ float rsh[4][2];
  const int t = blockIdx.x, tid = threadIdx.x, lane = tid & 63, w = tid >> 6;
  const size_t base = (size_t)t*1024 + tid*4;
  f32x4 xv = *(const f32x4*)(x + base);
  f32x4 av = *(const f32x4*)(a + base);
  f32x4 y = xv + av;
  float s1 = y.x + y.y + y.z + y.w;
  float s2 = y.x*y.x + y.y*y.y + y.z*y.z + y.w*y.w;
  #pragma unroll
  for (int off=32; off; off>>=1){ s1 += __shfl_down(s1, off); s2 += __shfl_down(s2, off); }
  if (lane==0){ rsh[w][0]=s1; rsh[w][1]=s2; }
  __syncthreads();
  const float ts1 = rsh[0][0]+rsh[1][0]+rsh[2][0]+rsh[3][0];
  const float ts2 = rsh[0][1]+rsh[1][1]+rsh[2][1]+rsh[3][1];
  const float mu = ts1*(1.f/1024.f);
  const float rinv = rsqrtf(ts2*(1.f/1024.f) - mu*mu + 1e-5f);
  f32x4 gv = *(const f32x4*)(g + tid*4);
  f32x4 bv = *(const f32x4*)(bb + tid*4);
  f32x4 ov;
  ov.x = (y.x-mu)*rinv*gv.x + bv.x;
  ov.y = (y.y-mu)*rinv*gv.y + bv.y;
  ov.z = (y.z-mu)*rinv*gv.z + bv.z;
  ov.w = (y.w-mu)*rinv*gv.w + bv.w;
  *(f32x4*)(out + base) = ov;
}

// ---------------- quantum FFN + residual + LN2, one block per token ----------------
// State: 256 complex amps; index i = r*64 + lane (r = bits 7:6, lane = bits 5:0).
// Wire w acts on bit p = 7-w (wire 0 = MSB).
__global__ __launch_bounds__(256) void k_qffn_ln(
    const float* __restrict__ x1,
    const float* __restrict__ Win, const float* __restrict__ b_in,
    const float* __restrict__ Wout, const float* __restrict__ b_out,
    const float* __restrict__ ry,
    const float* __restrict__ g2, const float* __restrict__ b2,
    float* __restrict__ out)
{
  __shared__ float redp[4][8];
  __shared__ float angs[8];
  __shared__ float ezs[8];
  __shared__ float rsh[4][2];
  const int t = blockIdx.x, tid = threadIdx.x, lane = tid & 63, w = tid >> 6;
  const size_t base = (size_t)t*1024 + tid*4;
  f32x4 xv = *(const f32x4*)(x1 + base);
  // angles = x1 . Win^T + b_in
  float pq[8];
  #pragma unroll
  for (int qq=0; qq<8; ++qq){
    f32x4 wv = *(const f32x4*)(Win + qq*1024 + tid*4);
    pq[qq] = wv.x*xv.x + wv.y*xv.y + wv.z*xv.z + wv.w*xv.w;
  }
  #pragma unroll
  for (int off=32; off; off>>=1)
    #pragma unroll
    for (int qq=0; qq<8; ++qq) pq[qq] += __shfl_down(pq[qq], off);
  if (lane==0){
    #pragma unroll
    for (int qq=0; qq<8; ++qq) redp[w][qq] = pq[qq];
  }
  __syncthreads();
  if (tid < 8) angs[tid] = redp[0][tid]+redp[1][tid]+redp[2][tid]+redp[3][tid] + b_in[tid];
  __syncthreads();
  if (w == 0){
    float vr[4], vi[4];
    #pragma unroll
    for (int r=0;r<4;++r){ vr[r]=0.f; vi[r]=0.f; }
    if (lane==0) vr[0] = 1.f;
    // RX(ang[wi]) per wire
    #pragma unroll
    for (int wi=0; wi<8; ++wi){
      float s, c; sincosf(angs[wi]*0.5f, &s, &c);
      const int p = 7 - wi;
      if (p >= 6){
        const int rp = 1 << (p-6);
        #pragma unroll
        for (int r=0;r<4;++r) if (!(r & rp)){
          const int r2 = r | rp;
          float ar=vr[r], ai=vi[r], br=vr[r2], bi=vi[r2];
          vr[r]  = c*ar + s*bi;  vi[r]  = c*ai - s*br;
          vr[r2] = c*br + s*ai;  vi[r2] = c*bi - s*ar;
        }
      } else {
        const int msk = 1 << p;
        #pragma unroll
        for (int r=0;r<4;++r){
          float orr = __shfl_xor(vr[r], msk);
          float oii = __shfl_xor(vi[r], msk);
          float nr = c*vr[r] + s*oii;
          float ni = c*vi[r] - s*orr;
          vr[r]=nr; vi[r]=ni;
        }
      }
    }
    // RY(ry[wi]) per wire (real rotation)
    #pragma unroll
    for (int wi=0; wi<8; ++wi){
      float s, c; sincosf(ry[wi]*0.5f, &s, &c);
      const int p = 7 - wi;
      if (p >= 6){
        const int rp = 1 << (p-6);
        #pragma unroll
        for (int r=0;r<4;++r) if (!(r & rp)){
          const int r2 = r | rp;
          float ar=vr[r], ai=vi[r], br=vr[r2], bi=vi[r2];
          vr[r]  = c*ar - s*br;  vi[r]  = c*ai - s*bi;
          vr[r2] = s*ar + c*br;  vi[r2] = s*ai + c*bi;
        }
      } else {
        const int msk = 1 << p;
        const float sg = (lane & msk) ? s : -s;
        #pragma unroll
        for (int r=0;r<4;++r){
          float orr = __shfl_xor(vr[r], msk);
          float oii = __shfl_xor(vi[r], msk);
          float nr = c*vr[r] + sg*orr;
          float ni = c*vi[r] + sg*oii;
          vr[r]=nr; vi[r]=ni;
        }
      }
    }
    // CNOT chain: c=0 (reg-bit1 -> reg-bit0): swap regs 2,3
    { float tr=vr[2]; vr[2]=vr[3]; vr[3]=tr; float ti=vi[2]; vi[2]=vi[3]; vi[3]=ti; }
    // c=1 (reg-bit0 -> lane-bit5): regs 1,3 exchange across lane^32
    vr[1]=__shfl_xor(vr[1],32); vi[1]=__shfl_xor(vi[1],32);
    vr[3]=__shfl_xor(vr[3],32); vi[3]=__shfl_xor(vi[3],32);
    // c=2..6: control lane-bit pc, target lane-bit pc-1
    #pragma unroll
    for (int cn=2; cn<7; ++cn){
      const int pc = 7-cn, pt = pc-1;
      const bool ctl = (lane >> pc) & 1;
      #pragma unroll
      for (int r=0;r<4;++r){
        float tr = __shfl_xor(vr[r], 1<<pt);
        float ti = __shfl_xor(vi[r], 1<<pt);
        if (ctl){ vr[r]=tr; vi[r]=ti; }
      }
    }
    // PauliZ expectations
    float pr[4];
    #pragma unroll
    for (int r=0;r<4;++r) pr[r] = vr[r]*vr[r] + vi[r]*vi[r];
    float e[8];
    e[0] = (pr[0]+pr[1]) - (pr[2]+pr[3]);     // bit7 = reg bit1
    e[1] = (pr[0]+pr[2]) - (pr[1]+pr[3]);     // bit6 = reg bit0
    const float tot = pr[0]+pr[1]+pr[2]+pr[3];
    #pragma unroll
    for (int wi=2; wi<8; ++wi){
      const int p = 7-wi;
      e[wi] = ((lane >> p) & 1) ? -tot : tot;
    }
    #pragma unroll
    for (int off=1; off<64; off<<=1)
      #pragma unroll
      for (int i=0;i<8;++i) e[i] += __shfl_xor(e[i], off);
    if (lane==0){
      #pragma unroll
      for (int i=0;i<8;++i) ezs[i] = e[i];
    }
  }
  __syncthreads();
  float ez[8];
  #pragma unroll
  for (int i=0;i<8;++i) ez[i] = ezs[i];
  const float xa[4] = {xv.x, xv.y, xv.z, xv.w};
  float y[4];
  #pragma unroll
  for (int j=0;j<4;++j){
    const int d = tid*4 + j;
    f32x4 w0 = *(const f32x4*)(Wout + (size_t)d*8);
    f32x4 w1 = *(const f32x4*)(Wout + (size_t)d*8 + 4);
    float acc = b_out[d];
    acc += w0.x*ez[0] + w0.y*ez[1] + w0.z*ez[2] + w0.w*ez[3];
    acc += w1.x*ez[4] + w1.y*ez[5] + w1.z*ez[6] + w1.w*ez[7];
    y[j] = xa[j] + fmaxf(acc, 0.f);
  }
  float s1 = y[0]+y[1]+y[2]+y[3];
  float s2 = y[0]*y[0]+y[1]*y[1]+y[2]*y[2]+y[3]*y[3];
  #pragma unroll
  for (int off=32; off; off>>=1){ s1 += __shfl_down(s1, off); s2 += __shfl_down(s2, off); }
  if (lane==0){ rsh[w][0]=s1; rsh[w][1]=s2; }
  __syncthreads();
  const float ts1 = rsh[0][0]+rsh[1][0]+rsh[2][0]+rsh[3][0];
  const float ts2 = rsh[0][1]+rsh[1][1]+rsh[2][1]+rsh[3][1];
  const float mu = ts1*(1.f/1024.f);
  const float rinv = rsqrtf(ts2*(1.f/1024.f) - mu*mu + 1e-5f);
  f32x4 gv = *(const f32x4*)(g2 + tid*4);
  f32x4 bv = *(const f32x4*)(b2 + tid*4);
  f32x4 ov;
  ov.x = (y[0]-mu)*rinv*gv.x + bv.x;
  ov.y = (y[1]-mu)*rinv*gv.y + bv.y;
  ov.z = (y[2]-mu)*rinv*gv.z + bv.z;
  ov.w = (y[3]-mu)*rinv*gv.w + bv.w;
  *(f32x4*)(out + base) = ov;
}

extern "C" void kernel_launch(void* const* d_in, const int* in_sizes, int n_in,
                              void* d_out, int out_size, void* d_ws, size_t ws_size,
                              hipStream_t stream)
{
  const float* x    = (const float*)d_in[0];
  const float* Wq   = (const float*)d_in[1];
  const float* Wk   = (const float*)d_in[2];
  const float* Wv   = (const float*)d_in[3];
  const float* Wo   = (const float*)d_in[4];
  const float* g1   = (const float*)d_in[5];
  const float* b1   = (const float*)d_in[6];
  const float* g2   = (const float*)d_in[7];
  const float* b2   = (const float*)d_in[8];
  const float* Win  = (const float*)d_in[9];
  const float* b_in = (const float*)d_in[10];
  const float* Wout = (const float*)d_in[11];
  const float* b_out= (const float*)d_in[12];
  const float* ry   = (const float*)d_in[13];
  float* out = (float*)d_out;
  char* ws = (char*)d_ws;
  const size_t MB = 1024u*1024u;
  u16* xb  = (u16*)(ws + 0*MB);    // x bf16            [4096][1024]   8 MB
  u16* wb  = (u16*)(ws + 8*MB);    // Wq|Wk|Wv bf16     [3072][1024]   6 MB
  u16* wob = (u16*)(ws + 14*MB);   // Wo bf16           [1024][1024]   2 MB
  u16* qb  = (u16*)(ws + 16*MB);   // q bf16 (/8)       [4096][1024]   8 MB
  u16* kb  = (u16*)(ws + 24*MB);   // k bf16                           8 MB
  u16* vb  = (u16*)(ws + 32*MB);   // v bf16                           8 MB
  u16* vtb = (u16*)(ws + 40*MB);   // v^T bf16 [32][64][2048]          8 MB
  u16* ob  = (u16*)(ws + 48*MB);   // attn o bf16                      8 MB
  float* attn_out = (float*)(ws + 16*MB); // f32, reuses q/k after attention (16 MB)
  float* x1       = (float*)(ws + 32*MB); // f32, reuses v/vt after attention (16 MB)

  k_cast<<<2048, 256, 0, stream>>>(x,  xb);
  k_cast<<<512,  256, 0, stream>>>(Wq, wb);
  k_cast<<<512,  256, 0, stream>>>(Wk, wb + 1024*1024);
  k_cast<<<512,  256, 0, stream>>>(Wv, wb + 2*1024*1024);
  k_cast<<<512,  256, 0, stream>>>(Wo, wob);
  k_gemm_nt<0><<<dim3(24,32), 256, 0, stream>>>(xb, wb, nullptr, qb, kb, vb, 1024, 3072);
  k_transpose_v<<<1024, 256, 0, stream>>>(vb, vtb);
  k_attn<<<512, 256, 0, stream>>>(qb, kb, vtb, ob);
  k_gemm_nt<1><<<dim3(8,32), 256, 0, stream>>>(ob, wob, attn_out, nullptr, nullptr, nullptr, 1024, 1024);
  k_add_ln<<<4096, 256, 0, stream>>>(x, attn_out, g1, b1, x1);
  k_qffn_ln<<<4096, 256, 0, stream>>>(x1, Win, b_in, Wout, b_out, ry, g2, b2, out);
}

// Round 2
// 279.209 us; speedup vs baseline: 1.3195x; 1.3195x over previous
//
#include <hip/hip_runtime.h>
#include <stdint.h>

// _TransformerBlockQuantum on MI355X (gfx950).
// cast->bf16 | fused QKV GEMM (+V-transpose epilogue) | flash attn (swapped QK^T,
// swizzled LDS, dbuf gload_lds) | Wo GEMM | fused LN1+quantum-FFN+LN2 tail.

typedef unsigned short u16;
typedef unsigned int   u32;
typedef __bf16 bf16x8 __attribute__((ext_vector_type(8)));
typedef u16    u16x8  __attribute__((ext_vector_type(8)));
typedef u16    u16x4  __attribute__((ext_vector_type(4)));
typedef float  f32x4  __attribute__((ext_vector_type(4)));

#define DEV static __device__ __forceinline__

DEV u16 f2b(float f){ u32 u = __float_as_uint(f); return (u16)((u + 0x7fffu + ((u>>16)&1u)) >> 16); }

#define MFMA16(a,b,c) __builtin_amdgcn_mfma_f32_16x16x32_bf16((a),(b),(c),0,0,0)
#define GLD16(gp,lp) __builtin_amdgcn_global_load_lds( \
    (const __attribute__((address_space(1))) u32*)(const void*)(gp), \
    (__attribute__((address_space(3))) u32*)(void*)(lp), 16, 0, 0)

// ---------------- cast f32 -> bf16, 8 elems/thread ----------------
__global__ __launch_bounds__(256) void k_cast(const float* __restrict__ src, u16* __restrict__ dst){
  const int i = blockIdx.x*256 + threadIdx.x;
  const f32x4* s = (const f32x4*)src + (size_t)i*2;
  f32x4 a = s[0], b = s[1];
  u16x8 o;
  o[0]=f2b(a.x); o[1]=f2b(a.y); o[2]=f2b(a.z); o[3]=f2b(a.w);
  o[4]=f2b(b.x); o[5]=f2b(b.y); o[6]=f2b(b.z); o[7]=f2b(b.w);
  ((u16x8*)dst)[i] = o;
}

// all 4 weight matrices in one launch: blocks [0,512)=Wq [512,1024)=Wk [1024,1536)=Wv [1536,2048)=Wo
__global__ __launch_bounds__(256) void k_cast_w(
    const float* __restrict__ Wq, const float* __restrict__ Wk,
    const float* __restrict__ Wv, const float* __restrict__ Wo,
    u16* __restrict__ wb, u16* __restrict__ wob){
  const int r = blockIdx.x >> 9, bi = blockIdx.x & 511;
  const float* src = (r==0)?Wq:((r==1)?Wk:((r==2)?Wv:Wo));
  u16* dst = (r<3) ? (wb + (size_t)r*1048576) : wob;
  const int i = bi*256 + threadIdx.x;
  const f32x4* s = (const f32x4*)src + (size_t)i*2;
  f32x4 a = s[0], b = s[1];
  u16x8 o;
  o[0]=f2b(a.x); o[1]=f2b(a.y); o[2]=f2b(a.z); o[3]=f2b(a.w);
  o[4]=f2b(b.x); o[5]=f2b(b.y); o[6]=f2b(b.z); o[7]=f2b(b.w);
  ((u16x8*)dst)[i] = o;
}

// ---------------- C = A * B^T  (A:[M,K] bf16, B:[N,K] bf16) ----------------
// MODE 0: N=3072 fused QKV epilogue -> q(*0.125)/k row-major; V transposed into vt[(b*16+h)*64+d][s]
// MODE 1: f32 epilogue into Cf[M][N]
template<int MODE>
__global__ __launch_bounds__(256) void k_gemm_nt(
    const u16* __restrict__ A, const u16* __restrict__ B,
    float* __restrict__ Cf, u16* __restrict__ Qo, u16* __restrict__ Ko, u16* __restrict__ Vt,
    int K, int N)
{
  __shared__ __attribute__((aligned(16))) u16 As[128*64];
  __shared__ __attribute__((aligned(16))) u16 Bs[128*64];
  const int tid = threadIdx.x, lane = tid & 63, w = tid >> 6;
  const int wr = w >> 1, wc = w & 1;
  const int m0 = blockIdx.y*128, n0 = blockIdx.x*128;
  const int l15 = lane & 15, lg = lane >> 4;
  f32x4 acc[4][4] = {};
  const int lr = lane >> 3, lc = (lane & 7)*8;
  const u16* ag = A + (size_t)(m0 + w*32 + lr)*K + lc;
  const u16* bg = B + (size_t)(n0 + w*32 + lr)*K + lc;
  u16* asl = &As[(w*32)*64];
  u16* bsl = &Bs[(w*32)*64];
  for (int k0 = 0; k0 < K; k0 += 64){
    __syncthreads();
    #pragma unroll
    for (int c = 0; c < 4; ++c){
      GLD16(ag + (size_t)(c*8)*K + k0, asl + c*512);
      GLD16(bg + (size_t)(c*8)*K + k0, bsl + c*512);
    }
    __syncthreads();
    #pragma unroll
    for (int kk = 0; kk < 2; ++kk){
      const int ko = kk*32 + lg*8;
      bf16x8 af[4], bf[4];
      #pragma unroll
      for (int t=0;t<4;++t) af[t] = *(const bf16x8*)&As[(wr*64 + t*16 + l15)*64 + ko];
      #pragma unroll
      for (int t=0;t<4;++t) bf[t] = *(const bf16x8*)&Bs[(wc*64 + t*16 + l15)*64 + ko];
      #pragma unroll
      for (int i=0;i<4;++i)
        #pragma unroll
        for (int j=0;j<4;++j)
          acc[i][j] = MFMA16(af[i], bf[j], acc[i][j]);
    }
  }
  const int col0 = n0 + wc*64 + l15;
  const int row0 = m0 + wr*64 + lg*4;
  if (MODE==0){
    const int which = n0 >> 10;   // uniform per block (128 | 1024)
    if (which == 2){
      // V -> vt[(b*16+h)*64+d][s], pack 4 consecutive s per store
      #pragma unroll
      for (int i=0;i<4;++i){
        const int rr0 = row0 + i*16;
        const int bsel = rr0 >> 11, ss = rr0 & 2047;
        #pragma unroll
        for (int j=0;j<4;++j){
          const int d_loc = (col0 + j*16) & 1023;
          const int hh = d_loc >> 6, dd = d_loc & 63;
          u16x4 pk;
          #pragma unroll
          for (int r=0;r<4;++r) pk[r] = f2b(acc[i][j][r]);
          *(u16x4*)(Vt + ((size_t)((bsel*16 + hh)*64 + dd))*2048 + ss) = pk;
        }
      }
    } else {
      u16* dst = which ? Ko : Qo;
      const float scl = which ? 1.f : 0.125f;
      #pragma unroll
      for (int i=0;i<4;++i)
      #pragma unroll
      for (int j=0;j<4;++j){
        const int cc = (col0 + j*16) & 1023;
        #pragma unroll
        for (int r=0;r<4;++r)
          dst[(size_t)(row0 + i*16 + r)*1024 + cc] = f2b(acc[i][j][r]*scl);
      }
    }
  } else {
    #pragma unroll
    for (int i=0;i<4;++i)
    #pragma unroll
    for (int j=0;j<4;++j){
      const int cc = col0 + j*16;
      #pragma unroll
      for (int r=0;r<4;++r)
        Cf[(size_t)(row0 + i*16 + r)*N + cc] = acc[i][j][r];
    }
  }
}

// ---------------- flash attention, swapped QK^T ----------------
// grid 1024: blockIdx = p*32 + qt; p=(b*16+h), qt = 64-row q tile. 4 waves x 16 q-rows.
// K/V double-buffered in swizzled LDS via global_load_lds with pre-swizzled source.
// Swizzle: byte addr = row*128 + (col_byte ^ ((row&7)<<4)).
__global__ __launch_bounds__(256) void k_attn(
    const u16* __restrict__ q, const u16* __restrict__ k,
    const u16* __restrict__ vt, u16* __restrict__ o)
{
  __shared__ __attribute__((aligned(16))) char KVb[2][16384]; // [buf][ K:8KB | V:8KB ]
  __shared__ __attribute__((aligned(16))) u16 Ps[4][1024];    // per-wave P [16 q][64 kv], swizzled
  const int tid = threadIdx.x, lane = tid & 63, w = tid >> 6;
  const int p = blockIdx.x >> 5, qt = blockIdx.x & 31;
  const int b = p >> 4, h = p & 15;
  const int t0 = b*2048 + qt*64 + w*16;
  const int l15 = lane & 15, lg = lane >> 4;
  const int swz = (l15 & 7) << 4;
  // Q fragment (B operand): col=q-row t0+l15, k-dim = d
  bf16x8 qa[2];
  #pragma unroll
  for (int kk=0;kk<2;++kk)
    qa[kk] = *(const bf16x8*)(q + (size_t)(t0 + l15)*1024 + h*64 + kk*32 + lg*8);
  // staging: slot s = w*2048 + i*1024 + lane*16 (byte in 8KB half); global source pre-swizzled
  const char* kgl[2]; const char* vgl[2]; int ldsK[2], ldsV[2];
  #pragma unroll
  for (int i=0;i<2;++i){
    const int s = w*2048 + i*1024 + lane*16;
    const int row = s >> 7;
    const int cb = (s & 127) ^ ((row & 7) << 4);
    kgl[i] = (const char*)k  + ((size_t)(b*2048 + row))*2048 + h*128 + cb; // + kv0*2048
    vgl[i] = (const char*)vt + ((size_t)(p*64    + row))*4096 + cb;       // + kv0*2
    ldsK[i] = w*2048 + i*1024;
    ldsV[i] = 8192 + w*2048 + i*1024;
  }
  f32x4 oacc[4] = {};
  float mrow = -1e30f, lrow = 0.f;
  int cur = 0;
  #pragma unroll
  for (int i=0;i<2;++i){ GLD16(kgl[i], KVb[0] + ldsK[i]); GLD16(vgl[i], KVb[0] + ldsV[i]); }
  for (int it = 0; it < 32; ++it){
    __syncthreads();   // drains gload_lds (vmcnt 0) + aligns waves
    if (it < 31){
      const size_t nkv = (size_t)(it+1)*64;
      #pragma unroll
      for (int i=0;i<2;++i){
        GLD16(kgl[i] + nkv*2048, KVb[cur^1] + ldsK[i]);
        GLD16(vgl[i] + nkv*2,    KVb[cur^1] + ldsV[i]);
      }
    }
    const char* Kb = KVb[cur];
    const char* Vb = KVb[cur] + 8192;
    // S^T tile: rows kv (A=K), cols q (B=Q). lane: q=l15, kv = nt*16+lg*4+r
    f32x4 sacc[4] = {};
    #pragma unroll
    for (int kk=0;kk<2;++kk){
      const int co = (kk*64 + lg*16) ^ swz;
      bf16x8 kbf[4];
      #pragma unroll
      for (int nt=0;nt<4;++nt) kbf[nt] = *(const bf16x8*)(Kb + (nt*16 + l15)*128 + co);
      #pragma unroll
      for (int nt=0;nt<4;++nt) sacc[nt] = MFMA16(kbf[nt], qa[kk], sacc[nt]);
    }
    // online softmax for q-row l15: 16 in-reg values + 2 shfl hops across lg
    float mx = sacc[0][0];
    #pragma unroll
    for (int nt=0;nt<4;++nt)
      #pragma unroll
      for (int r=0;r<4;++r) mx = fmaxf(mx, sacc[nt][r]);
    mx = fmaxf(mx, __shfl_xor(mx, 16));
    mx = fmaxf(mx, __shfl_xor(mx, 32));
    const float mnew = fmaxf(mrow, mx);
    const float scl = __expf(mrow - mnew);
    mrow = mnew;
    float rsum = 0.f;
    #pragma unroll
    for (int nt=0;nt<4;++nt)
      #pragma unroll
      for (int r=0;r<4;++r){ float e = __expf(sacc[nt][r] - mnew); sacc[nt][r] = e; rsum += e; }
    rsum += __shfl_xor(rsum, 16);
    rsum += __shfl_xor(rsum, 32);
    lrow = lrow*scl + rsum;
    // P write: row l15, cols nt*16+lg*4 .. +3  (packed b64, swizzled)
    char* Pw = (char*)&Ps[w][0];
    #pragma unroll
    for (int nt=0;nt<4;++nt){
      u16x4 pk;
      #pragma unroll
      for (int r=0;r<4;++r) pk[r] = f2b(sacc[nt][r]);
      *(u16x4*)(Pw + l15*128 + (((nt*16 + lg*4)*2) ^ swz)) = pk;
    }
    // rescale O rows (oacc row q = lg*4+r, scl lives at lane l15=lg*4+r)
    float sclo[4];
    #pragma unroll
    for (int r=0;r<4;++r) sclo[r] = __shfl(scl, lg*4 + r);
    #pragma unroll
    for (int nt=0;nt<4;++nt)
      #pragma unroll
      for (int r=0;r<4;++r) oacc[nt][r] *= sclo[r];
    // PV: A = P[q][kv] (row l15), B = V[d][kv]^T fragments from Vs[d][kv]
    #pragma unroll
    for (int kk=0;kk<2;++kk){
      const int co = (kk*64 + lg*16) ^ swz;
      bf16x8 pf = *(const bf16x8*)(Pw + l15*128 + co);
      bf16x8 vf[4];
      #pragma unroll
      for (int nt=0;nt<4;++nt) vf[nt] = *(const bf16x8*)(Vb + (nt*16 + l15)*128 + co);
      #pragma unroll
      for (int nt=0;nt<4;++nt) oacc[nt] = MFMA16(pf, vf[nt], oacc[nt]);
    }
    cur ^= 1;
  }
  float rl[4];
  #pragma unroll
  for (int r=0;r<4;++r){ float lf = __shfl(lrow, lg*4 + r); rl[r] = 1.f/lf; }
  #pragma unroll
  for (int nt=0;nt<4;++nt)
  #pragma unroll
  for (int r=0;r<4;++r)
    o[(size_t)(t0 + lg*4 + r)*1024 + h*64 + nt*16 + l15] = f2b(oacc[nt][r]*rl[r]);
}

// ---------------- fused tail: LN1(x+attn) -> quantum FFN -> +res -> LN2 ----------------
// one wave per token; 4 tokens/block; everything in registers + shuffles.
__global__ __launch_bounds__(256) void k_tail(
    const float* __restrict__ x, const float* __restrict__ attn,
    const float* __restrict__ g1, const float* __restrict__ b1,
    const float* __restrict__ Win, const float* __restrict__ b_in,
    const float* __restrict__ Wout, const float* __restrict__ b_out,
    const float* __restrict__ ry,
    const float* __restrict__ g2, const float* __restrict__ b2,
    float* __restrict__ out)
{
  const int tid = threadIdx.x, lane = tid & 63, w = tid >> 6;
  const int t = blockIdx.x*4 + w;
  const size_t base = (size_t)t*1024;
  // load row: lane owns cols {c*256 + lane*4 + j}
  f32x4 yv[4];
  float s1 = 0.f, s2 = 0.f;
  #pragma unroll
  for (int c=0;c<4;++c){
    const int idx = c*256 + lane*4;
    f32x4 xv = *(const f32x4*)(x + base + idx);
    f32x4 av = *(const f32x4*)(attn + base + idx);
    f32x4 y = xv + av;
    yv[c] = y;
    s1 += y.x + y.y + y.z + y.w;
    s2 += y.x*y.x + y.y*y.y + y.z*y.z + y.w*y.w;
  }
  #pragma unroll
  for (int off=32; off; off>>=1){ s1 += __shfl_xor(s1, off); s2 += __shfl_xor(s2, off); }
  {
    const float mu = s1*(1.f/1024.f);
    const float rinv = rsqrtf(s2*(1.f/1024.f) - mu*mu + 1e-5f);
    #pragma unroll
    for (int c=0;c<4;++c){
      const int idx = c*256 + lane*4;
      f32x4 gv = *(const f32x4*)(g1 + idx);
      f32x4 bv = *(const f32x4*)(b1 + idx);
      f32x4 y = yv[c];
      y.x = (y.x-mu)*rinv*gv.x + bv.x;
      y.y = (y.y-mu)*rinv*gv.y + bv.y;
      y.z = (y.z-mu)*rinv*gv.z + bv.z;
      y.w = (y.w-mu)*rinv*gv.w + bv.w;
      yv[c] = y;   // yv now holds x1
    }
  }
  // angles = x1 . Win^T + b_in
  float ang[8];
  #pragma unroll
  for (int qq=0; qq<8; ++qq){
    float acc = 0.f;
    #pragma unroll
    for (int c=0;c<4;++c){
      f32x4 wv = *(const f32x4*)(Win + qq*1024 + c*256 + lane*4);
      acc += wv.x*yv[c].x + wv.y*yv[c].y + wv.z*yv[c].z + wv.w*yv[c].w;
    }
    ang[qq] = acc;
  }
  #pragma unroll
  for (int off=32; off; off>>=1)
    #pragma unroll
    for (int qq=0; qq<8; ++qq) ang[qq] += __shfl_xor(ang[qq], off);
  #pragma unroll
  for (int qq=0; qq<8; ++qq) ang[qq] += b_in[qq];
  // 8-qubit sim: amp index i = r*64 + lane (r = bits 7:6). wire wi acts on bit 7-wi.
  float vr[4], vi[4];
  #pragma unroll
  for (int r=0;r<4;++r){ vr[r]=0.f; vi[r]=0.f; }
  if (lane==0) vr[0] = 1.f;
  #pragma unroll
  for (int wi=0; wi<8; ++wi){       // RX(ang)
    float s, c; __sincosf(ang[wi]*0.5f, &s, &c);
    const int pbit = 7 - wi;
    if (pbit >= 6){
      const int rp = 1 << (pbit-6);
      #pragma unroll
      for (int r=0;r<4;++r) if (!(r & rp)){
        const int r2 = r | rp;
        float ar=vr[r], ai=vi[r], br=vr[r2], bi=vi[r2];
        vr[r]  = c*ar + s*bi;  vi[r]  = c*ai - s*br;
        vr[r2] = c*br + s*ai;  vi[r2] = c*bi - s*ar;
      }
    } else {
      const int msk = 1 << pbit;
      #pragma unroll
      for (int r=0;r<4;++r){
        float orr = __shfl_xor(vr[r], msk);
        float oii = __shfl_xor(vi[r], msk);
        float nr = c*vr[r] + s*oii;
        float ni = c*vi[r] - s*orr;
        vr[r]=nr; vi[r]=ni;
      }
    }
  }
  #pragma unroll
  for (int wi=0; wi<8; ++wi){       // RY(ry)
    float s, c; __sincosf(ry[wi]*0.5f, &s, &c);
    const int pbit = 7 - wi;
    if (pbit >= 6){
      const int rp = 1 << (pbit-6);
      #pragma unroll
      for (int r=0;r<4;++r) if (!(r & rp)){
        const int r2 = r | rp;
        float ar=vr[r], ai=vi[r], br=vr[r2], bi=vi[r2];
        vr[r]  = c*ar - s*br;  vi[r]  = c*ai - s*bi;
        vr[r2] = s*ar + c*br;  vi[r2] = s*ai + c*bi;
      }
    } else {
      const int msk = 1 << pbit;
      const float sg = (lane & msk) ? s : -s;
      #pragma unroll
      for (int r=0;r<4;++r){
        float orr = __shfl_xor(vr[r], msk);
        float oii = __shfl_xor(vi[r], msk);
        float nr = c*vr[r] + sg*orr;
        float ni = c*vi[r] + sg*oii;
        vr[r]=nr; vi[r]=ni;
      }
    }
  }
  // CNOT chain
  { float tr=vr[2]; vr[2]=vr[3]; vr[3]=tr; float ti=vi[2]; vi[2]=vi[3]; vi[3]=ti; }
  vr[1]=__shfl_xor(vr[1],32); vi[1]=__shfl_xor(vi[1],32);
  vr[3]=__shfl_xor(vr[3],32); vi[3]=__shfl_xor(vi[3],32);
  #pragma unroll
  for (int cn=2; cn<7; ++cn){
    const int pc = 7-cn, pt = pc-1;
    const bool ctl = (lane >> pc) & 1;
    #pragma unroll
    for (int r=0;r<4;++r){
      float tr = __shfl_xor(vr[r], 1<<pt);
      float ti = __shfl_xor(vi[r], 1<<pt);
      if (ctl){ vr[r]=tr; vi[r]=ti; }
    }
  }
  // PauliZ expectations
  float pr[4];
  #pragma unroll
  for (int r=0;r<4;++r) pr[r] = vr[r]*vr[r] + vi[r]*vi[r];
  float e[8];
  e[0] = (pr[0]+pr[1]) - (pr[2]+pr[3]);
  e[1] = (pr[0]+pr[2]) - (pr[1]+pr[3]);
  const float tot = pr[0]+pr[1]+pr[2]+pr[3];
  #pragma unroll
  for (int wi=2; wi<8; ++wi){
    const int pbit = 7-wi;
    e[wi] = ((lane >> pbit) & 1) ? -tot : tot;
  }
  #pragma unroll
  for (int off=1; off<64; off<<=1)
    #pragma unroll
    for (int i=0;i<8;++i) e[i] += __shfl_xor(e[i], off);
  // out proj + ReLU + residual + LN2
  float yy[4][4];
  s1 = 0.f; s2 = 0.f;
  #pragma unroll
  for (int c=0;c<4;++c){
    const float x1a[4] = {yv[c].x, yv[c].y, yv[c].z, yv[c].w};
    #pragma unroll
    for (int j=0;j<4;++j){
      const int d = c*256 + lane*4 + j;
      f32x4 w0 = *(const f32x4*)(Wout + (size_t)d*8);
      f32x4 w1 = *(const f32x4*)(Wout + (size_t)d*8 + 4);
      float acc = b_out[d];
      acc += w0.x*e[0] + w0.y*e[1] + w0.z*e[2] + w0.w*e[3];
      acc += w1.x*e[4] + w1.y*e[5] + w1.z*e[6] + w1.w*e[7];
      const float y = x1a[j] + fmaxf(acc, 0.f);
      yy[c][j] = y;
      s1 += y; s2 += y*y;
    }
  }
  #pragma unroll
  for (int off=32; off; off>>=1){ s1 += __shfl_xor(s1, off); s2 += __shfl_xor(s2, off); }
  const float mu = s1*(1.f/1024.f);
  const float rinv = rsqrtf(s2*(1.f/1024.f) - mu*mu + 1e-5f);
  #pragma unroll
  for (int c=0;c<4;++c){
    const int idx = c*256 + lane*4;
    f32x4 gv = *(const f32x4*)(g2 + idx);
    f32x4 bv = *(const f32x4*)(b2 + idx);
    f32x4 ov;
    ov.x = (yy[c][0]-mu)*rinv*gv.x + bv.x;
    ov.y = (yy[c][1]-mu)*rinv*gv.y + bv.y;
    ov.z = (yy[c][2]-mu)*rinv*gv.z + bv.z;
    ov.w = (yy[c][3]-mu)*rinv*gv.w + bv.w;
    *(f32x4*)(out + base + idx) = ov;
  }
}

extern "C" void kernel_launch(void* const* d_in, const int* in_sizes, int n_in,
                              void* d_out, int out_size, void* d_ws, size_t ws_size,
                              hipStream_t stream)
{
  const float* x    = (const float*)d_in[0];
  const float* Wq   = (const float*)d_in[1];
  const float* Wk   = (const float*)d_in[2];
  const float* Wv   = (const float*)d_in[3];
  const float* Wo   = (const float*)d_in[4];
  const float* g1   = (const float*)d_in[5];
  const float* b1   = (const float*)d_in[6];
  const float* g2   = (const float*)d_in[7];
  const float* b2   = (const float*)d_in[8];
  const float* Win  = (const float*)d_in[9];
  const float* b_in = (const float*)d_in[10];
  const float* Wout = (const float*)d_in[11];
  const float* b_out= (const float*)d_in[12];
  const float* ry   = (const float*)d_in[13];
  float* out = (float*)d_out;
  char* ws = (char*)d_ws;
  const size_t MB = 1024u*1024u;
  u16* xb  = (u16*)(ws + 0*MB);    // x bf16            [4096][1024]   8 MB
  u16* wb  = (u16*)(ws + 8*MB);    // Wq|Wk|Wv bf16     [3072][1024]   6 MB
  u16* wob = (u16*)(ws + 14*MB);   // Wo bf16           [1024][1024]   2 MB
  u16* qb  = (u16*)(ws + 16*MB);   // q bf16 (/8)       [4096][1024]   8 MB
  u16* kb  = (u16*)(ws + 24*MB);   // k bf16                           8 MB
  u16* vtb = (u16*)(ws + 32*MB);   // v^T bf16 [32*64][2048]           8 MB
  u16* ob  = (u16*)(ws + 40*MB);   // attn o bf16                      8 MB
  float* attn_out = (float*)(ws + 48*MB); // f32 [4096][1024]          16 MB

  k_cast<<<2048, 256, 0, stream>>>(x, xb);
  k_cast_w<<<2048, 256, 0, stream>>>(Wq, Wk, Wv, Wo, wb, wob);
  k_gemm_nt<0><<<dim3(24,32), 256, 0, stream>>>(xb, wb, nullptr, qb, kb, vtb, 1024, 3072);
  k_attn<<<1024, 256, 0, stream>>>(qb, kb, vtb, ob);
  k_gemm_nt<1><<<dim3(8,32), 256, 0, stream>>>(ob, wob, attn_out, nullptr, nullptr, nullptr, 1024, 1024);
  k_tail<<<1024, 256, 0, stream>>>(x, attn_out, g1, b1, Win, b_in, Wout, b_out, ry, g2, b2, out);
}

// Round 4
// 270.443 us; speedup vs baseline: 1.3623x; 1.0324x over previous
//
#include <hip/hip_runtime.h>
#include <stdint.h>

// _TransformerBlockQuantum on MI355X (gfx950).
// cast->bf16 | fused QKV GEMM (+V-transpose epilogue) | flash attn (swapped QK^T,
// 32q/wave, log2-domain softmax, defer-max, swizzled LDS, dbuf gload_lds)
// | Wo GEMM | fused LN1+quantum-FFN+LN2 tail.

typedef unsigned short u16;
typedef unsigned int   u32;
typedef __bf16 bf16x8 __attribute__((ext_vector_type(8)));
typedef u16    u16x8  __attribute__((ext_vector_type(8)));
typedef u16    u16x4  __attribute__((ext_vector_type(4)));
typedef float  f32x4  __attribute__((ext_vector_type(4)));

#define DEV static __device__ __forceinline__

DEV u16 f2b(float f){ u32 u = __float_as_uint(f); return (u16)((u + 0x7fffu + ((u>>16)&1u)) >> 16); }
DEV u16 b2u(__bf16 h){ union{__bf16 b; u16 u;} c; c.b = h; return c.u; }
DEV float exp2fast(float x){ return __builtin_amdgcn_exp2f(x); }  // v_exp_f32 (2^x)

#define MFMA16(a,b,c) __builtin_amdgcn_mfma_f32_16x16x32_bf16((a),(b),(c),0,0,0)
#define GLD16(gp,lp) __builtin_amdgcn_global_load_lds( \
    (const __attribute__((address_space(1))) u32*)(const void*)(gp), \
    (__attribute__((address_space(3))) u32*)(void*)(lp), 16, 0, 0)

// ---------------- cast f32 -> bf16, 8 elems/thread ----------------
__global__ __launch_bounds__(256) void k_cast(const float* __restrict__ src, u16* __restrict__ dst){
  const int i = blockIdx.x*256 + threadIdx.x;
  const f32x4* s = (const f32x4*)src + (size_t)i*2;
  f32x4 a = s[0], b = s[1];
  u16x8 o;
  o[0]=f2b(a.x); o[1]=f2b(a.y); o[2]=f2b(a.z); o[3]=f2b(a.w);
  o[4]=f2b(b.x); o[5]=f2b(b.y); o[6]=f2b(b.z); o[7]=f2b(b.w);
  ((u16x8*)dst)[i] = o;
}

// all 4 weight matrices in one launch
__global__ __launch_bounds__(256) void k_cast_w(
    const float* __restrict__ Wq, const float* __restrict__ Wk,
    const float* __restrict__ Wv, const float* __restrict__ Wo,
    u16* __restrict__ wb, u16* __restrict__ wob){
  const int r = blockIdx.x >> 9, bi = blockIdx.x & 511;
  const float* src = (r==0)?Wq:((r==1)?Wk:((r==2)?Wv:Wo));
  u16* dst = (r<3) ? (wb + (size_t)r*1048576) : wob;
  const int i = bi*256 + threadIdx.x;
  const f32x4* s = (const f32x4*)src + (size_t)i*2;
  f32x4 a = s[0], b = s[1];
  u16x8 o;
  o[0]=f2b(a.x); o[1]=f2b(a.y); o[2]=f2b(a.z); o[3]=f2b(a.w);
  o[4]=f2b(b.x); o[5]=f2b(b.y); o[6]=f2b(b.z); o[7]=f2b(b.w);
  ((u16x8*)dst)[i] = o;
}

// ---------------- C = A * B^T  (A:[M,K] bf16, B:[N,K] bf16) ----------------
// MODE 0: N=3072 fused QKV epilogue -> q(*0.125*log2e)/k row-major; V -> vt[(p*64+d)][s]
// MODE 1: f32 epilogue into Cf[M][N]
template<int MODE>
__global__ __launch_bounds__(256) void k_gemm_nt(
    const u16* __restrict__ A, const u16* __restrict__ B,
    float* __restrict__ Cf, u16* __restrict__ Qo, u16* __restrict__ Ko, u16* __restrict__ Vt,
    int K, int N)
{
  __shared__ __attribute__((aligned(16))) u16 As[128*64];
  __shared__ __attribute__((aligned(16))) u16 Bs[128*64];
  const int tid = threadIdx.x, lane = tid & 63, w = tid >> 6;
  const int wr = w >> 1, wc = w & 1;
  const int m0 = blockIdx.y*128, n0 = blockIdx.x*128;
  const int l15 = lane & 15, lg = lane >> 4;
  f32x4 acc[4][4] = {};
  const int lr = lane >> 3, lc = (lane & 7)*8;
  const u16* ag = A + (size_t)(m0 + w*32 + lr)*K + lc;
  const u16* bg = B + (size_t)(n0 + w*32 + lr)*K + lc;
  u16* asl = &As[(w*32)*64];
  u16* bsl = &Bs[(w*32)*64];
  for (int k0 = 0; k0 < K; k0 += 64){
    __syncthreads();
    #pragma unroll
    for (int c = 0; c < 4; ++c){
      GLD16(ag + (size_t)(c*8)*K + k0, asl + c*512);
      GLD16(bg + (size_t)(c*8)*K + k0, bsl + c*512);
    }
    __syncthreads();
    #pragma unroll
    for (int kk = 0; kk < 2; ++kk){
      const int ko = kk*32 + lg*8;
      bf16x8 af[4], bf[4];
      #pragma unroll
      for (int t=0;t<4;++t) af[t] = *(const bf16x8*)&As[(wr*64 + t*16 + l15)*64 + ko];
      #pragma unroll
      for (int t=0;t<4;++t) bf[t] = *(const bf16x8*)&Bs[(wc*64 + t*16 + l15)*64 + ko];
      #pragma unroll
      for (int i=0;i<4;++i)
        #pragma unroll
        for (int j=0;j<4;++j)
          acc[i][j] = MFMA16(af[i], bf[j], acc[i][j]);
    }
  }
  const int col0 = n0 + wc*64 + l15;
  const int row0 = m0 + wr*64 + lg*4;
  if (MODE==0){
    const int which = n0 >> 10;   // uniform per block
    if (which == 2){
      #pragma unroll
      for (int i=0;i<4;++i){
        const int rr0 = row0 + i*16;
        const int bsel = rr0 >> 11, ss = rr0 & 2047;
        #pragma unroll
        for (int j=0;j<4;++j){
          const int d_loc = (col0 + j*16) & 1023;
          const int hh = d_loc >> 6, dd = d_loc & 63;
          u16x4 pk;
          #pragma unroll
          for (int r=0;r<4;++r) pk[r] = f2b(acc[i][j][r]);
          *(u16x4*)(Vt + ((size_t)((bsel*16 + hh)*64 + dd))*2048 + ss) = pk;
        }
      }
    } else {
      u16* dst = which ? Ko : Qo;
      const float scl = which ? 1.f : 0.125f*1.44269504f;  // fold log2(e) into q
      #pragma unroll
      for (int i=0;i<4;++i)
      #pragma unroll
      for (int j=0;j<4;++j){
        const int cc = (col0 + j*16) & 1023;
        #pragma unroll
        for (int r=0;r<4;++r)
          dst[(size_t)(row0 + i*16 + r)*1024 + cc] = f2b(acc[i][j][r]*scl);
      }
    }
  } else {
    #pragma unroll
    for (int i=0;i<4;++i)
    #pragma unroll
    for (int j=0;j<4;++j){
      const int cc = col0 + j*16;
      #pragma unroll
      for (int r=0;r<4;++r)
        Cf[(size_t)(row0 + i*16 + r)*N + cc] = acc[i][j][r];
    }
  }
}

// ---------------- flash attention, swapped QK^T, 32 q-rows per wave ----------------
// grid 512: blockIdx = p*16 + qt; p=(b*16+h), qt = 128-row q tile. 4 waves x 32 q-rows.
// Scores are in log2 domain (q pre-scaled by 0.125*log2e); softmax uses exp2.
// Swizzle: byte addr = row*128 + (col_byte ^ ((row&7)<<4)).
__global__ __launch_bounds__(256) void k_attn(
    const u16* __restrict__ q, const u16* __restrict__ k,
    const u16* __restrict__ vt, u16* __restrict__ o)
{
  __shared__ __attribute__((aligned(16))) char KVb[2][16384]; // [buf][ K:8KB | V:8KB ]
  __shared__ __attribute__((aligned(16))) u16 Ps[4][2048];    // per-wave P [32 q][64 kv], swizzled
  const int tid = threadIdx.x, lane = tid & 63, w = tid >> 6;
  const int p = blockIdx.x >> 4, qt = blockIdx.x & 15;
  const int b = p >> 4, h = p & 15;
  const int t0 = b*2048 + qt*128 + w*32;
  const int l15 = lane & 15, lg = lane >> 4;
  const int swz = (l15 & 7) << 4;
  // Q fragments (B operand): col = q-row, k-dim = d
  bf16x8 qa[2][2];
  #pragma unroll
  for (int mt=0;mt<2;++mt)
  #pragma unroll
  for (int kk=0;kk<2;++kk)
    qa[mt][kk] = *(const bf16x8*)(q + (size_t)(t0 + mt*16 + l15)*1024 + h*64 + kk*32 + lg*8);
  // staging: per-wave slot; global source pre-swizzled so LDS dest stays linear
  const char* kgl[2]; const char* vgl[2]; int ldsK[2], ldsV[2];
  #pragma unroll
  for (int i=0;i<2;++i){
    const int s = w*2048 + i*1024 + lane*16;
    const int row = s >> 7;
    const int cb = (s & 127) ^ ((row & 7) << 4);
    kgl[i] = (const char*)k  + ((size_t)(b*2048 + row))*2048 + h*128 + cb; // + kv0*2048
    vgl[i] = (const char*)vt + ((size_t)(p*64    + row))*4096 + cb;       // + kv0*2
    ldsK[i] = w*2048 + i*1024;
    ldsV[i] = 8192 + w*2048 + i*1024;
  }
  f32x4 oacc[2][4] = {};
  float mrow[2] = {-1e30f, -1e30f}, lrow[2] = {0.f, 0.f};
  int cur = 0;
  #pragma unroll
  for (int i=0;i<2;++i){ GLD16(kgl[i], KVb[0] + ldsK[i]); GLD16(vgl[i], KVb[0] + ldsV[i]); }
  for (int it = 0; it < 32; ++it){
    __syncthreads();   // drains gload_lds + aligns waves
    if (it < 31){
      const size_t nkv = (size_t)(it+1)*64;
      #pragma unroll
      for (int i=0;i<2;++i){
        GLD16(kgl[i] + nkv*2048, KVb[cur^1] + ldsK[i]);
        GLD16(vgl[i] + nkv*2,    KVb[cur^1] + ldsV[i]);
      }
    }
    const char* Kb = KVb[cur];
    const char* Vb = KVb[cur] + 8192;
    // S^T tiles: rows kv (A=K frag, shared across mt), cols q (B=Q)
    f32x4 sacc[2][4] = {};
    #pragma unroll
    for (int kk=0;kk<2;++kk){
      const int co = (kk*64 + lg*16) ^ swz;
      bf16x8 kbf[4];
      #pragma unroll
      for (int nt=0;nt<4;++nt) kbf[nt] = *(const bf16x8*)(Kb + (nt*16 + l15)*128 + co);
      #pragma unroll
      for (int mt=0;mt<2;++mt)
      #pragma unroll
      for (int nt=0;nt<4;++nt)
        sacc[mt][nt] = MFMA16(kbf[nt], qa[mt][kk], sacc[mt][nt]);
    }
    // online softmax (log2 domain) for q-rows l15 (mt=0) and 16+l15 (mt=1)
    float mx[2];
    #pragma unroll
    for (int mt=0;mt<2;++mt){
      float m = sacc[mt][0][0];
      #pragma unroll
      for (int nt=0;nt<4;++nt)
        #pragma unroll
        for (int r=0;r<4;++r) m = fmaxf(m, sacc[mt][nt][r]);
      m = fmaxf(m, __shfl_xor(m, 16));
      m = fmaxf(m, __shfl_xor(m, 32));
      mx[mt] = m;
    }
    // defer-max: only rescale when some row's max grew by > 8 (2^8 headroom)
    const int ok = (mx[0] <= mrow[0] + 8.f) && (mx[1] <= mrow[1] + 8.f);
    if (!__all(ok)){
      #pragma unroll
      for (int mt=0;mt<2;++mt){
        const float mnew = fmaxf(mrow[mt], mx[mt]);
        const float scl = exp2fast(mrow[mt] - mnew);
        mrow[mt] = mnew;
        lrow[mt] *= scl;
        float sclo[4];
        #pragma unroll
        for (int r=0;r<4;++r) sclo[r] = __shfl(scl, lg*4 + r);
        #pragma unroll
        for (int nt=0;nt<4;++nt)
          #pragma unroll
          for (int r=0;r<4;++r) oacc[mt][nt][r] *= sclo[r];
      }
    }
    char* Pw = (char*)&Ps[w][0];
    #pragma unroll
    for (int mt=0;mt<2;++mt){
      float rsum = 0.f;
      #pragma unroll
      for (int nt=0;nt<4;++nt)
        #pragma unroll
        for (int r=0;r<4;++r){
          float e = exp2fast(sacc[mt][nt][r] - mrow[mt]);
          sacc[mt][nt][r] = e;
          rsum += e;
        }
      rsum += __shfl_xor(rsum, 16);
      rsum += __shfl_xor(rsum, 32);
      lrow[mt] += rsum;
      // P write: row mt*16+l15, cols nt*16+lg*4 .. +3 (packed b64, swizzled)
      #pragma unroll
      for (int nt=0;nt<4;++nt){
        u16x4 pk;
        #pragma unroll
        for (int r=0;r<4;++r) pk[r] = b2u((__bf16)sacc[mt][nt][r]);
        *(u16x4*)(Pw + (mt*16 + l15)*128 + (((nt*16 + lg*4)*2) ^ swz)) = pk;
      }
    }
    // PV: A = P[q][kv], B = V^T fragments from Vs[d][kv]
    #pragma unroll
    for (int kk=0;kk<2;++kk){
      const int co = (kk*64 + lg*16) ^ swz;
      bf16x8 pf[2], vf[4];
      #pragma unroll
      for (int mt=0;mt<2;++mt) pf[mt] = *(const bf16x8*)(Pw + (mt*16 + l15)*128 + co);
      #pragma unroll
      for (int nt=0;nt<4;++nt) vf[nt] = *(const bf16x8*)(Vb + (nt*16 + l15)*128 + co);
      #pragma unroll
      for (int mt=0;mt<2;++mt)
      #pragma unroll
      for (int nt=0;nt<4;++nt)
        oacc[mt][nt] = MFMA16(pf[mt], vf[nt], oacc[mt][nt]);
    }
    cur ^= 1;
  }
  #pragma unroll
  for (int mt=0;mt<2;++mt){
    float rl[4];
    #pragma unroll
    for (int r=0;r<4;++r){ float lf = __shfl(lrow[mt], lg*4 + r); rl[r] = 1.f/lf; }
    #pragma unroll
    for (int nt=0;nt<4;++nt)
    #pragma unroll
    for (int r=0;r<4;++r)
      o[(size_t)(t0 + mt*16 + lg*4 + r)*1024 + h*64 + nt*16 + l15] = b2u((__bf16)(oacc[mt][nt][r]*rl[r]));
  }
}

// ---------------- fused tail: LN1(x+attn) -> quantum FFN -> +res -> LN2 ----------------
__global__ __launch_bounds__(256) void k_tail(
    const float* __restrict__ x, const float* __restrict__ attn,
    const float* __restrict__ g1, const float* __restrict__ b1,
    const float* __restrict__ Win, const float* __restrict__ b_in,
    const float* __restrict__ Wout, const float* __restrict__ b_out,
    const float* __restrict__ ry,
    const float* __restrict__ g2, const float* __restrict__ b2,
    float* __restrict__ out)
{
  const int tid = threadIdx.x, lane = tid & 63, w = tid >> 6;
  const int t = blockIdx.x*4 + w;
  const size_t base = (size_t)t*1024;
  f32x4 yv[4];
  float s1 = 0.f, s2 = 0.f;
  #pragma unroll
  for (int c=0;c<4;++c){
    const int idx = c*256 + lane*4;
    f32x4 xv = *(const f32x4*)(x + base + idx);
    f32x4 av = *(const f32x4*)(attn + base + idx);
    f32x4 y = xv + av;
    yv[c] = y;
    s1 += y.x + y.y + y.z + y.w;
    s2 += y.x*y.x + y.y*y.y + y.z*y.z + y.w*y.w;
  }
  #pragma unroll
  for (int off=32; off; off>>=1){ s1 += __shfl_xor(s1, off); s2 += __shfl_xor(s2, off); }
  {
    const float mu = s1*(1.f/1024.f);
    const float rinv = rsqrtf(s2*(1.f/1024.f) - mu*mu + 1e-5f);
    #pragma unroll
    for (int c=0;c<4;++c){
      const int idx = c*256 + lane*4;
      f32x4 gv = *(const f32x4*)(g1 + idx);
      f32x4 bv = *(const f32x4*)(b1 + idx);
      f32x4 y = yv[c];
      y.x = (y.x-mu)*rinv*gv.x + bv.x;
      y.y = (y.y-mu)*rinv*gv.y + bv.y;
      y.z = (y.z-mu)*rinv*gv.z + bv.z;
      y.w = (y.w-mu)*rinv*gv.w + bv.w;
      yv[c] = y;
    }
  }
  float ang[8];
  #pragma unroll
  for (int qq=0; qq<8; ++qq){
    float acc = 0.f;
    #pragma unroll
    for (int c=0;c<4;++c){
      f32x4 wv = *(const f32x4*)(Win + qq*1024 + c*256 + lane*4);
      acc += wv.x*yv[c].x + wv.y*yv[c].y + wv.z*yv[c].z + wv.w*yv[c].w;
    }
    ang[qq] = acc;
  }
  #pragma unroll
  for (int off=32; off; off>>=1)
    #pragma unroll
    for (int qq=0; qq<8; ++qq) ang[qq] += __shfl_xor(ang[qq], off);
  #pragma unroll
  for (int qq=0; qq<8; ++qq) ang[qq] += b_in[qq];
  float vr[4], vi[4];
  #pragma unroll
  for (int r=0;r<4;++r){ vr[r]=0.f; vi[r]=0.f; }
  if (lane==0) vr[0] = 1.f;
  #pragma unroll
  for (int wi=0; wi<8; ++wi){       // RX(ang)
    float s, c; __sincosf(ang[wi]*0.5f, &s, &c);
    const int pbit = 7 - wi;
    if (pbit >= 6){
      const int rp = 1 << (pbit-6);
      #pragma unroll
      for (int r=0;r<4;++r) if (!(r & rp)){
        const int r2 = r | rp;
        float ar=vr[r], ai=vi[r], br=vr[r2], bi=vi[r2];
        vr[r]  = c*ar + s*bi;  vi[r]  = c*ai - s*br;
        vr[r2] = c*br + s*ai;  vi[r2] = c*bi - s*ar;
      }
    } else {
      const int msk = 1 << pbit;
      #pragma unroll
      for (int r=0;r<4;++r){
        float orr = __shfl_xor(vr[r], msk);
        float oii = __shfl_xor(vi[r], msk);
        float nr = c*vr[r] + s*oii;
        float ni = c*vi[r] - s*orr;
        vr[r]=nr; vi[r]=ni;
      }
    }
  }
  #pragma unroll
  for (int wi=0; wi<8; ++wi){       // RY(ry)
    float s, c; __sincosf(ry[wi]*0.5f, &s, &c);
    const int pbit = 7 - wi;
    if (pbit >= 6){
      const int rp = 1 << (pbit-6);
      #pragma unroll
      for (int r=0;r<4;++r) if (!(r & rp)){
        const int r2 = r | rp;
        float ar=vr[r], ai=vi[r], br=vr[r2], bi=vi[r2];
        vr[r]  = c*ar - s*br;  vi[r]  = c*ai - s*bi;
        vr[r2] = s*ar + c*br;  vi[r2] = s*ai + c*bi;
      }
    } else {
      const int msk = 1 << pbit;
      const float sg = (lane & msk) ? s : -s;
      #pragma unroll
      for (int r=0;r<4;++r){
        float orr = __shfl_xor(vr[r], msk);
        float oii = __shfl_xor(vi[r], msk);
        float nr = c*vr[r] + sg*orr;
        float ni = c*vi[r] + sg*oii;
        vr[r]=nr; vi[r]=ni;
      }
    }
  }
  { float tr=vr[2]; vr[2]=vr[3]; vr[3]=tr; float ti=vi[2]; vi[2]=vi[3]; vi[3]=ti; }
  vr[1]=__shfl_xor(vr[1],32); vi[1]=__shfl_xor(vi[1],32);
  vr[3]=__shfl_xor(vr[3],32); vi[3]=__shfl_xor(vi[3],32);
  #pragma unroll
  for (int cn=2; cn<7; ++cn){
    const int pc = 7-cn, pt = pc-1;
    const bool ctl = (lane >> pc) & 1;
    #pragma unroll
    for (int r=0;r<4;++r){
      float tr = __shfl_xor(vr[r], 1<<pt);
      float ti = __shfl_xor(vi[r], 1<<pt);
      if (ctl){ vr[r]=tr; vi[r]=ti; }
    }
  }
  float pr[4];
  #pragma unroll
  for (int r=0;r<4;++r) pr[r] = vr[r]*vr[r] + vi[r]*vi[r];
  float e[8];
  e[0] = (pr[0]+pr[1]) - (pr[2]+pr[3]);
  e[1] = (pr[0]+pr[2]) - (pr[1]+pr[3]);
  const float tot = pr[0]+pr[1]+pr[2]+pr[3];
  #pragma unroll
  for (int wi=2; wi<8; ++wi){
    const int pbit = 7-wi;
    e[wi] = ((lane >> pbit) & 1) ? -tot : tot;
  }
  #pragma unroll
  for (int off=1; off<64; off<<=1)
    #pragma unroll
    for (int i=0;i<8;++i) e[i] += __shfl_xor(e[i], off);
  float yy[4][4];
  s1 = 0.f; s2 = 0.f;
  #pragma unroll
  for (int c=0;c<4;++c){
    const float x1a[4] = {yv[c].x, yv[c].y, yv[c].z, yv[c].w};
    #pragma unroll
    for (int j=0;j<4;++j){
      const int d = c*256 + lane*4 + j;
      f32x4 w0 = *(const f32x4*)(Wout + (size_t)d*8);
      f32x4 w1 = *(const f32x4*)(Wout + (size_t)d*8 + 4);
      float acc = b_out[d];
      acc += w0.x*e[0] + w0.y*e[1] + w0.z*e[2] + w0.w*e[3];
      acc += w1.x*e[4] + w1.y*e[5] + w1.z*e[6] + w1.w*e[7];
      const float y = x1a[j] + fmaxf(acc, 0.f);
      yy[c][j] = y;
      s1 += y; s2 += y*y;
    }
  }
  #pragma unroll
  for (int off=32; off; off>>=1){ s1 += __shfl_xor(s1, off); s2 += __shfl_xor(s2, off); }
  const float mu = s1*(1.f/1024.f);
  const float rinv = rsqrtf(s2*(1.f/1024.f) - mu*mu + 1e-5f);
  #pragma unroll
  for (int c=0;c<4;++c){
    const int idx = c*256 + lane*4;
    f32x4 gv = *(const f32x4*)(g2 + idx);
    f32x4 bv = *(const f32x4*)(b2 + idx);
    f32x4 ov;
    ov.x = (yy[c][0]-mu)*rinv*gv.x + bv.x;
    ov.y = (yy[c][1]-mu)*rinv*gv.y + bv.y;
    ov.z = (yy[c][2]-mu)*rinv*gv.z + bv.z;
    ov.w = (yy[c][3]-mu)*rinv*gv.w + bv.w;
    *(f32x4*)(out + base + idx) = ov;
  }
}

extern "C" void kernel_launch(void* const* d_in, const int* in_sizes, int n_in,
                              void* d_out, int out_size, void* d_ws, size_t ws_size,
                              hipStream_t stream)
{
  const float* x    = (const float*)d_in[0];
  const float* Wq   = (const float*)d_in[1];
  const float* Wk   = (const float*)d_in[2];
  const float* Wv   = (const float*)d_in[3];
  const float* Wo   = (const float*)d_in[4];
  const float* g1   = (const float*)d_in[5];
  const float* b1   = (const float*)d_in[6];
  const float* g2   = (const float*)d_in[7];
  const float* b2   = (const float*)d_in[8];
  const float* Win  = (const float*)d_in[9];
  const float* b_in = (const float*)d_in[10];
  const float* Wout = (const float*)d_in[11];
  const float* b_out= (const float*)d_in[12];
  const float* ry   = (const float*)d_in[13];
  float* out = (float*)d_out;
  char* ws = (char*)d_ws;
  const size_t MB = 1024u*1024u;
  u16* xb  = (u16*)(ws + 0*MB);
  u16* wb  = (u16*)(ws + 8*MB);
  u16* wob = (u16*)(ws + 14*MB);
  u16* qb  = (u16*)(ws + 16*MB);
  u16* kb  = (u16*)(ws + 24*MB);
  u16* vtb = (u16*)(ws + 32*MB);
  u16* ob  = (u16*)(ws + 40*MB);
  float* attn_out = (float*)(ws + 48*MB);

  k_cast<<<2048, 256, 0, stream>>>(x, xb);
  k_cast_w<<<2048, 256, 0, stream>>>(Wq, Wk, Wv, Wo, wb, wob);
  k_gemm_nt<0><<<dim3(24,32), 256, 0, stream>>>(xb, wb, nullptr, qb, kb, vtb, 1024, 3072);
  k_attn<<<512, 256, 0, stream>>>(qb, kb, vtb, ob);
  k_gemm_nt<1><<<dim3(8,32), 256, 0, stream>>>(ob, wob, attn_out, nullptr, nullptr, nullptr, 1024, 1024);
  k_tail<<<1024, 256, 0, stream>>>(x, attn_out, g1, b1, Win, b_in, Wout, b_out, ry, g2, b2, out);
}

// Round 5
// 268.915 us; speedup vs baseline: 1.3700x; 1.0057x over previous
//
#include <hip/hip_runtime.h>
#include <stdint.h>

// _TransformerBlockQuantum on MI355X (gfx950).
// cast->bf16 | fused QKV GEMM (+V-transpose epilogue, XCD swizzle) | flash attn
// (32x32 MFMA, swapped QK^T and PV, in-register P via permlane32_swap, log2 softmax,
// defer-max, swizzled LDS, dbuf gload_lds, setprio) | Wo GEMM | fused tail.

typedef unsigned short u16;
typedef unsigned int   u32;
typedef __bf16 bf16x8 __attribute__((ext_vector_type(8)));
typedef u16    u16x8  __attribute__((ext_vector_type(8)));
typedef u16    u16x4  __attribute__((ext_vector_type(4)));
typedef float  f32x4  __attribute__((ext_vector_type(4)));
typedef float  f32x16 __attribute__((ext_vector_type(16)));

#define DEV static __device__ __forceinline__

DEV u16 f2b(float f){ u32 u = __float_as_uint(f); return (u16)((u + 0x7fffu + ((u>>16)&1u)) >> 16); }
DEV u16 b2u(__bf16 h){ union{__bf16 b; u16 u;} c; c.b = h; return c.u; }
DEV float exp2fast(float x){ return __builtin_amdgcn_exp2f(x); }  // v_exp_f32 (2^x)

// permlane32_swap(a,b): out0 = (lane<32) ? a(own) : b(partner); out1 = (lane<32) ? a(partner) : b(own)
DEV void plswap(u32 a, u32 b, u32& o0, u32& o1, int hi){
#if __has_builtin(__builtin_amdgcn_permlane32_swap)
  auto s = __builtin_amdgcn_permlane32_swap(a, b, false, false);
  o0 = s[0]; o1 = s[1];
#else
  u32 xa = __shfl_xor(a, 32), xb = __shfl_xor(b, 32);
  o0 = hi ? xb : a;
  o1 = hi ? b  : xa;
#endif
}

#define MFMA16(a,b,c) __builtin_amdgcn_mfma_f32_16x16x32_bf16((a),(b),(c),0,0,0)
#define MFMA32(a,b,c) __builtin_amdgcn_mfma_f32_32x32x16_bf16((a),(b),(c),0,0,0)
#define GLD16(gp,lp) __builtin_amdgcn_global_load_lds( \
    (const __attribute__((address_space(1))) u32*)(const void*)(gp), \
    (__attribute__((address_space(3))) u32*)(void*)(lp), 16, 0, 0)

// ---------------- cast f32 -> bf16, 8 elems/thread ----------------
__global__ __launch_bounds__(256) void k_cast(const float* __restrict__ src, u16* __restrict__ dst){
  const int i = blockIdx.x*256 + threadIdx.x;
  const f32x4* s = (const f32x4*)src + (size_t)i*2;
  f32x4 a = s[0], b = s[1];
  u16x8 o;
  o[0]=f2b(a.x); o[1]=f2b(a.y); o[2]=f2b(a.z); o[3]=f2b(a.w);
  o[4]=f2b(b.x); o[5]=f2b(b.y); o[6]=f2b(b.z); o[7]=f2b(b.w);
  ((u16x8*)dst)[i] = o;
}

// all 4 weight matrices in one launch
__global__ __launch_bounds__(256) void k_cast_w(
    const float* __restrict__ Wq, const float* __restrict__ Wk,
    const float* __restrict__ Wv, const float* __restrict__ Wo,
    u16* __restrict__ wb, u16* __restrict__ wob){
  const int r = blockIdx.x >> 9, bi = blockIdx.x & 511;
  const float* src = (r==0)?Wq:((r==1)?Wk:((r==2)?Wv:Wo));
  u16* dst = (r<3) ? (wb + (size_t)r*1048576) : wob;
  const int i = bi*256 + threadIdx.x;
  const f32x4* s = (const f32x4*)src + (size_t)i*2;
  f32x4 a = s[0], b = s[1];
  u16x8 o;
  o[0]=f2b(a.x); o[1]=f2b(a.y); o[2]=f2b(a.z); o[3]=f2b(a.w);
  o[4]=f2b(b.x); o[5]=f2b(b.y); o[6]=f2b(b.z); o[7]=f2b(b.w);
  ((u16x8*)dst)[i] = o;
}

// ---------------- C = A * B^T  (A:[M,K] bf16, B:[N,K] bf16) ----------------
// XCD-aware bijective block swizzle (nwg % 8 == 0 for both launches).
// MODE 0: N=3072 fused QKV epilogue -> q(*0.125*log2e)/k row-major; V -> vt[(p*64+d)][s]
// MODE 1: f32 epilogue into Cf[M][N]
template<int MODE>
__global__ __launch_bounds__(256) void k_gemm_nt(
    const u16* __restrict__ A, const u16* __restrict__ B,
    float* __restrict__ Cf, u16* __restrict__ Qo, u16* __restrict__ Ko, u16* __restrict__ Vt,
    int K, int N)
{
  __shared__ __attribute__((aligned(16))) u16 As[128*64];
  __shared__ __attribute__((aligned(16))) u16 Bs[128*64];
  const int tid = threadIdx.x, lane = tid & 63, w = tid >> 6;
  const int wr = w >> 1, wc = w & 1;
  // XCD swizzle: chunk tile space per XCD
  const int nwg = gridDim.x * gridDim.y;
  int lin = blockIdx.y * gridDim.x + blockIdx.x;
  lin = (lin & 7) * (nwg >> 3) + (lin >> 3);
  const int n0 = (lin % gridDim.x) * 128;
  const int m0 = (lin / gridDim.x) * 128;
  const int l15 = lane & 15, lg = lane >> 4;
  f32x4 acc[4][4] = {};
  const int lr = lane >> 3, lc = (lane & 7)*8;
  const u16* ag = A + (size_t)(m0 + w*32 + lr)*K + lc;
  const u16* bg = B + (size_t)(n0 + w*32 + lr)*K + lc;
  u16* asl = &As[(w*32)*64];
  u16* bsl = &Bs[(w*32)*64];
  for (int k0 = 0; k0 < K; k0 += 64){
    __syncthreads();
    #pragma unroll
    for (int c = 0; c < 4; ++c){
      GLD16(ag + (size_t)(c*8)*K + k0, asl + c*512);
      GLD16(bg + (size_t)(c*8)*K + k0, bsl + c*512);
    }
    __syncthreads();
    #pragma unroll
    for (int kk = 0; kk < 2; ++kk){
      const int ko = kk*32 + lg*8;
      bf16x8 af[4], bf[4];
      #pragma unroll
      for (int t=0;t<4;++t) af[t] = *(const bf16x8*)&As[(wr*64 + t*16 + l15)*64 + ko];
      #pragma unroll
      for (int t=0;t<4;++t) bf[t] = *(const bf16x8*)&Bs[(wc*64 + t*16 + l15)*64 + ko];
      #pragma unroll
      for (int i=0;i<4;++i)
        #pragma unroll
        for (int j=0;j<4;++j)
          acc[i][j] = MFMA16(af[i], bf[j], acc[i][j]);
    }
  }
  const int col0 = n0 + wc*64 + l15;
  const int row0 = m0 + wr*64 + lg*4;
  if (MODE==0){
    const int which = n0 >> 10;   // uniform per block
    if (which == 2){
      #pragma unroll
      for (int i=0;i<4;++i){
        const int rr0 = row0 + i*16;
        const int bsel = rr0 >> 11, ss = rr0 & 2047;
        #pragma unroll
        for (int j=0;j<4;++j){
          const int d_loc = (col0 + j*16) & 1023;
          const int hh = d_loc >> 6, dd = d_loc & 63;
          u16x4 pk;
          #pragma unroll
          for (int r=0;r<4;++r) pk[r] = f2b(acc[i][j][r]);
          *(u16x4*)(Vt + ((size_t)((bsel*16 + hh)*64 + dd))*2048 + ss) = pk;
        }
      }
    } else {
      u16* dst = which ? Ko : Qo;
      const float scl = which ? 1.f : 0.125f*1.44269504f;  // fold log2(e) into q
      #pragma unroll
      for (int i=0;i<4;++i)
      #pragma unroll
      for (int j=0;j<4;++j){
        const int cc = (col0 + j*16) & 1023;
        #pragma unroll
        for (int r=0;r<4;++r)
          dst[(size_t)(row0 + i*16 + r)*1024 + cc] = f2b(acc[i][j][r]*scl);
      }
    }
  } else {
    #pragma unroll
    for (int i=0;i<4;++i)
    #pragma unroll
    for (int j=0;j<4;++j){
      const int cc = col0 + j*16;
      #pragma unroll
      for (int r=0;r<4;++r)
        Cf[(size_t)(row0 + i*16 + r)*N + cc] = acc[i][j][r];
    }
  }
}

// ---------------- flash attention, 32x32 MFMA, in-register P ----------------
// grid 512: blockIdx = p*16 + qt; p=(b*16+h). 4 waves x 32 q-rows = 128 q/block.
// q pre-scaled by 0.125*log2e; softmax in log2 domain (exp2).
// Lane: q = lane&31, hi = lane>>5.
// QK^T: S^T[kv][q] = MFMA32(Kfrag, Qfrag); lane holds full 64-kv row of its q
//   across sacc[2][16] (+ partner for the complementary 4-kv interleave).
// PV:   O^T[d][q] = MFMA32(Vfrag, Pfrag); P fragments built in-register via
//   16 packed bf16 cvts + 8 permlane32_swap. No P LDS roundtrip.
__global__ __launch_bounds__(256) void k_attn(
    const u16* __restrict__ q, const u16* __restrict__ k,
    const u16* __restrict__ vt, u16* __restrict__ o)
{
  __shared__ __attribute__((aligned(16))) char KVb[2][16384]; // [buf][ K:8KB | V:8KB ]
  const int tid = threadIdx.x, lane = tid & 63, w = tid >> 6;
  const int p = blockIdx.x >> 4, qt = blockIdx.x & 15;
  const int b = p >> 4, h = p & 15;
  const int l31 = lane & 31, hi = lane >> 5;
  const int qrow = b*2048 + qt*128 + w*32 + l31;
  const int swz = (l31 & 7) << 4;
  // Q fragments (B operand): col=q (lane l31), k-dim = d = kk*16 + hi*8 + j
  bf16x8 qa[4];
  #pragma unroll
  for (int kk=0;kk<4;++kk)
    qa[kk] = *(const bf16x8*)(q + (size_t)qrow*1024 + h*64 + kk*16 + hi*8);
  // staging: per-wave slot; global source pre-swizzled so LDS dest stays linear
  const char* kgl[2]; const char* vgl[2]; int ldsK[2], ldsV[2];
  #pragma unroll
  for (int i=0;i<2;++i){
    const int s = w*2048 + i*1024 + lane*16;
    const int row = s >> 7;
    const int cb = (s & 127) ^ ((row & 7) << 4);
    kgl[i] = (const char*)k  + ((size_t)(b*2048 + row))*2048 + h*128 + cb; // + kv0*2048
    vgl[i] = (const char*)vt + ((size_t)(p*64    + row))*4096 + cb;       // + kv0*2
    ldsK[i] = w*2048 + i*1024;
    ldsV[i] = 8192 + w*2048 + i*1024;
  }
  f32x16 oacc[2] = {};
  float mrow = -1e30f, lrow = 0.f;
  int cur = 0;
  #pragma unroll
  for (int i=0;i<2;++i){ GLD16(kgl[i], KVb[0] + ldsK[i]); GLD16(vgl[i], KVb[0] + ldsV[i]); }
  for (int it = 0; it < 32; ++it){
    __syncthreads();   // drains gload_lds + aligns waves
    if (it < 31){
      const size_t nkv = (size_t)(it+1)*64;
      #pragma unroll
      for (int i=0;i<2;++i){
        GLD16(kgl[i] + nkv*2048, KVb[cur^1] + ldsK[i]);
        GLD16(vgl[i] + nkv*2,    KVb[cur^1] + ldsV[i]);
      }
    }
    const char* Kb = KVb[cur];
    const char* Vb = KVb[cur] + 8192;
    // QK^T: two 32x32 tiles over kv, accumulate K=64 in 4 slices
    f32x16 sacc[2] = {};
    __builtin_amdgcn_s_setprio(1);
    #pragma unroll
    for (int t32=0;t32<2;++t32){
      const int row = t32*32 + l31;
      #pragma unroll
      for (int kk=0;kk<4;++kk){
        bf16x8 kf = *(const bf16x8*)(Kb + row*128 + ((kk*32 + hi*16) ^ swz));
        sacc[t32] = MFMA32(kf, qa[kk], sacc[t32]);
      }
    }
    __builtin_amdgcn_s_setprio(0);
    // online softmax (log2 domain), row q = l31; partner (lane^32) holds the
    // complementary kv interleave of the same row.
    float mx = sacc[0][0];
    #pragma unroll
    for (int t32=0;t32<2;++t32)
      #pragma unroll
      for (int i=0;i<16;++i) mx = fmaxf(mx, sacc[t32][i]);
    mx = fmaxf(mx, __shfl_xor(mx, 32));
    if (!__all(mx <= mrow + 8.f)){       // defer-max: rescale only on >2^8 growth
      const float mnew = fmaxf(mrow, mx);
      const float scl = exp2fast(mrow - mnew);
      mrow = mnew; lrow *= scl;
      #pragma unroll
      for (int dt=0;dt<2;++dt)
        #pragma unroll
        for (int i=0;i<16;++i) oacc[dt][i] *= scl;
    }
    float rsum = 0.f;
    #pragma unroll
    for (int t32=0;t32<2;++t32)
      #pragma unroll
      for (int i=0;i<16;++i){
        const float e = exp2fast(sacc[t32][i] - mrow);
        sacc[t32][i] = e; rsum += e;
      }
    rsum += __shfl_xor(rsum, 32);
    lrow += rsum;
    // pack P to bf16 pairs: pk[t32][2*rg+hf] = (p[4rg+2hf], p[4rg+2hf+1])
    u32 pk[2][8];
    #pragma unroll
    for (int t32=0;t32<2;++t32)
      #pragma unroll
      for (int u=0;u<8;++u){
        const int idx = (u>>1)*4 + (u&1)*2;
        const u32 lo = b2u((__bf16)sacc[t32][idx]);
        const u32 hh = b2u((__bf16)sacc[t32][idx+1]);
        pk[t32][u] = lo | (hh << 16);
      }
    // PV B-frags: lane needs P[q=l31][kv = op*16 + hi*8 + j], j=0..7
    bf16x8 pb[4];
    #pragma unroll
    for (int op=0;op<4;++op){
      const int t32 = op>>1, base = (op&1)*4;
      u32 w0,w1,w2,w3;
      plswap(pk[t32][base+0], pk[t32][base+2], w0, w2, hi);
      plswap(pk[t32][base+1], pk[t32][base+3], w1, w3, hi);
      union { u32 u[4]; bf16x8 v; } cc;
      cc.u[0]=w0; cc.u[1]=w1; cc.u[2]=w2; cc.u[3]=w3;
      pb[op] = cc.v;
    }
    // PV: O^T[d][q], two 32-d tiles, kv=64 in 4 slices
    __builtin_amdgcn_s_setprio(1);
    #pragma unroll
    for (int dt=0;dt<2;++dt){
      const int row = dt*32 + l31;
      #pragma unroll
      for (int op=0;op<4;++op){
        bf16x8 vf = *(const bf16x8*)(Vb + row*128 + ((op*32 + hi*16) ^ swz));
        oacc[dt] = MFMA32(vf, pb[op], oacc[dt]);
      }
    }
    __builtin_amdgcn_s_setprio(0);
    cur ^= 1;
  }
  // epilogue: O[q][d] = O^T[d][q]/l; d = dt*32 + 8*rg + 4*hi + (reg&3)
  const float rinv = 1.f / lrow;
  u16* orow = o + (size_t)qrow*1024 + h*64;
  #pragma unroll
  for (int dt=0;dt<2;++dt)
    #pragma unroll
    for (int rg=0;rg<4;++rg)
      #pragma unroll
      for (int hf=0;hf<2;++hf){
        const int r0 = rg*4 + hf*2;
        const u32 lo = b2u((__bf16)(oacc[dt][r0]   * rinv));
        const u32 hh = b2u((__bf16)(oacc[dt][r0+1] * rinv));
        *(u32*)(orow + dt*32 + rg*8 + hi*4 + hf*2) = lo | (hh << 16);
      }
}

// ---------------- fused tail: LN1(x+attn) -> quantum FFN -> +res -> LN2 ----------------
__global__ __launch_bounds__(256) void k_tail(
    const float* __restrict__ x, const float* __restrict__ attn,
    const float* __restrict__ g1, const float* __restrict__ b1,
    const float* __restrict__ Win, const float* __restrict__ b_in,
    const float* __restrict__ Wout, const float* __restrict__ b_out,
    const float* __restrict__ ry,
    const float* __restrict__ g2, const float* __restrict__ b2,
    float* __restrict__ out)
{
  const int tid = threadIdx.x, lane = tid & 63, w = tid >> 6;
  const int t = blockIdx.x*4 + w;
  const size_t base = (size_t)t*1024;
  f32x4 yv[4];
  float s1 = 0.f, s2 = 0.f;
  #pragma unroll
  for (int c=0;c<4;++c){
    const int idx = c*256 + lane*4;
    f32x4 xv = *(const f32x4*)(x + base + idx);
    f32x4 av = *(const f32x4*)(attn + base + idx);
    f32x4 y = xv + av;
    yv[c] = y;
    s1 += y.x + y.y + y.z + y.w;
    s2 += y.x*y.x + y.y*y.y + y.z*y.z + y.w*y.w;
  }
  #pragma unroll
  for (int off=32; off; off>>=1){ s1 += __shfl_xor(s1, off); s2 += __shfl_xor(s2, off); }
  {
    const float mu = s1*(1.f/1024.f);
    const float rinv = rsqrtf(s2*(1.f/1024.f) - mu*mu + 1e-5f);
    #pragma unroll
    for (int c=0;c<4;++c){
      const int idx = c*256 + lane*4;
      f32x4 gv = *(const f32x4*)(g1 + idx);
      f32x4 bv = *(const f32x4*)(b1 + idx);
      f32x4 y = yv[c];
      y.x = (y.x-mu)*rinv*gv.x + bv.x;
      y.y = (y.y-mu)*rinv*gv.y + bv.y;
      y.z = (y.z-mu)*rinv*gv.z + bv.z;
      y.w = (y.w-mu)*rinv*gv.w + bv.w;
      yv[c] = y;
    }
  }
  float ang[8];
  #pragma unroll
  for (int qq=0; qq<8; ++qq){
    float acc = 0.f;
    #pragma unroll
    for (int c=0;c<4;++c){
      f32x4 wv = *(const f32x4*)(Win + qq*1024 + c*256 + lane*4);
      acc += wv.x*yv[c].x + wv.y*yv[c].y + wv.z*yv[c].z + wv.w*yv[c].w;
    }
    ang[qq] = acc;
  }
  #pragma unroll
  for (int off=32; off; off>>=1)
    #pragma unroll
    for (int qq=0; qq<8; ++qq) ang[qq] += __shfl_xor(ang[qq], off);
  #pragma unroll
  for (int qq=0; qq<8; ++qq) ang[qq] += b_in[qq];
  float vr[4], vi[4];
  #pragma unroll
  for (int r=0;r<4;++r){ vr[r]=0.f; vi[r]=0.f; }
  if (lane==0) vr[0] = 1.f;
  #pragma unroll
  for (int wi=0; wi<8; ++wi){       // RX(ang)
    float s, c; __sincosf(ang[wi]*0.5f, &s, &c);
    const int pbit = 7 - wi;
    if (pbit >= 6){
      const int rp = 1 << (pbit-6);
      #pragma unroll
      for (int r=0;r<4;++r) if (!(r & rp)){
        const int r2 = r | rp;
        float ar=vr[r], ai=vi[r], br=vr[r2], bi=vi[r2];
        vr[r]  = c*ar + s*bi;  vi[r]  = c*ai - s*br;
        vr[r2] = c*br + s*ai;  vi[r2] = c*bi - s*ar;
      }
    } else {
      const int msk = 1 << pbit;
      #pragma unroll
      for (int r=0;r<4;++r){
        float orr = __shfl_xor(vr[r], msk);
        float oii = __shfl_xor(vi[r], msk);
        float nr = c*vr[r] + s*oii;
        float ni = c*vi[r] - s*orr;
        vr[r]=nr; vi[r]=ni;
      }
    }
  }
  #pragma unroll
  for (int wi=0; wi<8; ++wi){       // RY(ry)
    float s, c; __sincosf(ry[wi]*0.5f, &s, &c);
    const int pbit = 7 - wi;
    if (pbit >= 6){
      const int rp = 1 << (pbit-6);
      #pragma unroll
      for (int r=0;r<4;++r) if (!(r & rp)){
        const int r2 = r | rp;
        float ar=vr[r], ai=vi[r], br=vr[r2], bi=vi[r2];
        vr[r]  = c*ar - s*br;  vi[r]  = c*ai - s*bi;
        vr[r2] = s*ar + c*br;  vi[r2] = s*ai + c*bi;
      }
    } else {
      const int msk = 1 << pbit;
      const float sg = (lane & msk) ? s : -s;
      #pragma unroll
      for (int r=0;r<4;++r){
        float orr = __shfl_xor(vr[r], msk);
        float oii = __shfl_xor(vi[r], msk);
        float nr = c*vr[r] + sg*orr;
        float ni = c*vi[r] + sg*oii;
        vr[r]=nr; vi[r]=ni;
      }
    }
  }
  { float tr=vr[2]; vr[2]=vr[3]; vr[3]=tr; float ti=vi[2]; vi[2]=vi[3]; vi[3]=ti; }
  vr[1]=__shfl_xor(vr[1],32); vi[1]=__shfl_xor(vi[1],32);
  vr[3]=__shfl_xor(vr[3],32); vi[3]=__shfl_xor(vi[3],32);
  #pragma unroll
  for (int cn=2; cn<7; ++cn){
    const int pc = 7-cn, pt = pc-1;
    const bool ctl = (lane >> pc) & 1;
    #pragma unroll
    for (int r=0;r<4;++r){
      float tr = __shfl_xor(vr[r], 1<<pt);
      float ti = __shfl_xor(vi[r], 1<<pt);
      if (ctl){ vr[r]=tr; vi[r]=ti; }
    }
  }
  float pr[4];
  #pragma unroll
  for (int r=0;r<4;++r) pr[r] = vr[r]*vr[r] + vi[r]*vi[r];
  float e[8];
  e[0] = (pr[0]+pr[1]) - (pr[2]+pr[3]);
  e[1] = (pr[0]+pr[2]) - (pr[1]+pr[3]);
  const float tot = pr[0]+pr[1]+pr[2]+pr[3];
  #pragma unroll
  for (int wi=2; wi<8; ++wi){
    const int pbit = 7-wi;
    e[wi] = ((lane >> pbit) & 1) ? -tot : tot;
  }
  #pragma unroll
  for (int off=1; off<64; off<<=1)
    #pragma unroll
    for (int i=0;i<8;++i) e[i] += __shfl_xor(e[i], off);
  float yy[4][4];
  s1 = 0.f; s2 = 0.f;
  #pragma unroll
  for (int c=0;c<4;++c){
    const float x1a[4] = {yv[c].x, yv[c].y, yv[c].z, yv[c].w};
    #pragma unroll
    for (int j=0;j<4;++j){
      const int d = c*256 + lane*4 + j;
      f32x4 w0 = *(const f32x4*)(Wout + (size_t)d*8);
      f32x4 w1 = *(const f32x4*)(Wout + (size_t)d*8 + 4);
      float acc = b_out[d];
      acc += w0.x*e[0] + w0.y*e[1] + w0.z*e[2] + w0.w*e[3];
      acc += w1.x*e[4] + w1.y*e[5] + w1.z*e[6] + w1.w*e[7];
      const float y = x1a[j] + fmaxf(acc, 0.f);
      yy[c][j] = y;
      s1 += y; s2 += y*y;
    }
  }
  #pragma unroll
  for (int off=32; off; off>>=1){ s1 += __shfl_xor(s1, off); s2 += __shfl_xor(s2, off); }
  const float mu = s1*(1.f/1024.f);
  const float rinv = rsqrtf(s2*(1.f/1024.f) - mu*mu + 1e-5f);
  #pragma unroll
  for (int c=0;c<4;++c){
    const int idx = c*256 + lane*4;
    f32x4 gv = *(const f32x4*)(g2 + idx);
    f32x4 bv = *(const f32x4*)(b2 + idx);
    f32x4 ov;
    ov.x = (yy[c][0]-mu)*rinv*gv.x + bv.x;
    ov.y = (yy[c][1]-mu)*rinv*gv.y + bv.y;
    ov.z = (yy[c][2]-mu)*rinv*gv.z + bv.z;
    ov.w = (yy[c][3]-mu)*rinv*gv.w + bv.w;
    *(f32x4*)(out + base + idx) = ov;
  }
}

extern "C" void kernel_launch(void* const* d_in, const int* in_sizes, int n_in,
                              void* d_out, int out_size, void* d_ws, size_t ws_size,
                              hipStream_t stream)
{
  const float* x    = (const float*)d_in[0];
  const float* Wq   = (const float*)d_in[1];
  const float* Wk   = (const float*)d_in[2];
  const float* Wv   = (const float*)d_in[3];
  const float* Wo   = (const float*)d_in[4];
  const float* g1   = (const float*)d_in[5];
  const float* b1   = (const float*)d_in[6];
  const float* g2   = (const float*)d_in[7];
  const float* b2   = (const float*)d_in[8];
  const float* Win  = (const float*)d_in[9];
  const float* b_in = (const float*)d_in[10];
  const float* Wout = (const float*)d_in[11];
  const float* b_out= (const float*)d_in[12];
  const float* ry   = (const float*)d_in[13];
  float* out = (float*)d_out;
  char* ws = (char*)d_ws;
  const size_t MB = 1024u*1024u;
  u16* xb  = (u16*)(ws + 0*MB);
  u16* wb  = (u16*)(ws + 8*MB);
  u16* wob = (u16*)(ws + 14*MB);
  u16* qb  = (u16*)(ws + 16*MB);
  u16* kb  = (u16*)(ws + 24*MB);
  u16* vtb = (u16*)(ws + 32*MB);
  u16* ob  = (u16*)(ws + 40*MB);
  float* attn_out = (float*)(ws + 48*MB);

  k_cast<<<2048, 256, 0, stream>>>(x, xb);
  k_cast_w<<<2048, 256, 0, stream>>>(Wq, Wk, Wv, Wo, wb, wob);
  k_gemm_nt<0><<<dim3(24,32), 256, 0, stream>>>(xb, wb, nullptr, qb, kb, vtb, 1024, 3072);
  k_attn<<<512, 256, 0, stream>>>(qb, kb, vtb, ob);
  k_gemm_nt<1><<<dim3(8,32), 256, 0, stream>>>(ob, wob, attn_out, nullptr, nullptr, nullptr, 1024, 1024);
  k_tail<<<1024, 256, 0, stream>>>(x, attn_out, g1, b1, Win, b_in, Wout, b_out, ry, g2, b2, out);
}

// Round 6
// 266.419 us; speedup vs baseline: 1.3828x; 1.0094x over previous
//
#include <hip/hip_runtime.h>
#include <stdint.h>

// _TransformerBlockQuantum on MI355X (gfx950).
// cast->bf16 | fused QKV GEMM (+V-transpose epilogue, XCD swizzle) | flash attn
// (in-block kv-split: 8 waves = 2 groups x 4, 32x32 MFMA, in-register P via
// permlane32_swap, log2 softmax, defer-max, swizzled LDS, dbuf gload_lds, LDS merge)
// | Wo GEMM | fused tail.

typedef unsigned short u16;
typedef unsigned int   u32;
typedef __bf16 bf16x8 __attribute__((ext_vector_type(8)));
typedef u16    u16x8  __attribute__((ext_vector_type(8)));
typedef u16    u16x4  __attribute__((ext_vector_type(4)));
typedef float  f32x4  __attribute__((ext_vector_type(4)));
typedef float  f32x16 __attribute__((ext_vector_type(16)));

#define DEV static __device__ __forceinline__

DEV u16 f2b(float f){ u32 u = __float_as_uint(f); return (u16)((u + 0x7fffu + ((u>>16)&1u)) >> 16); }
DEV u16 b2u(__bf16 h){ union{__bf16 b; u16 u;} c; c.b = h; return c.u; }
DEV float exp2fast(float x){ return __builtin_amdgcn_exp2f(x); }  // v_exp_f32 (2^x)

// permlane32_swap(a,b): out0 = (lane<32) ? a(own) : b(partner); out1 = (lane<32) ? a(partner) : b(own)
DEV void plswap(u32 a, u32 b, u32& o0, u32& o1, int hi){
#if __has_builtin(__builtin_amdgcn_permlane32_swap)
  auto s = __builtin_amdgcn_permlane32_swap(a, b, false, false);
  o0 = s[0]; o1 = s[1];
#else
  u32 xa = __shfl_xor(a, 32), xb = __shfl_xor(b, 32);
  o0 = hi ? xb : a;
  o1 = hi ? b  : xa;
#endif
}

#define MFMA16(a,b,c) __builtin_amdgcn_mfma_f32_16x16x32_bf16((a),(b),(c),0,0,0)
#define MFMA32(a,b,c) __builtin_amdgcn_mfma_f32_32x32x16_bf16((a),(b),(c),0,0,0)
#define GLD16(gp,lp) __builtin_amdgcn_global_load_lds( \
    (const __attribute__((address_space(1))) u32*)(const void*)(gp), \
    (__attribute__((address_space(3))) u32*)(void*)(lp), 16, 0, 0)

// ---------------- cast f32 -> bf16, 8 elems/thread ----------------
__global__ __launch_bounds__(256) void k_cast(const float* __restrict__ src, u16* __restrict__ dst){
  const int i = blockIdx.x*256 + threadIdx.x;
  const f32x4* s = (const f32x4*)src + (size_t)i*2;
  f32x4 a = s[0], b = s[1];
  u16x8 o;
  o[0]=f2b(a.x); o[1]=f2b(a.y); o[2]=f2b(a.z); o[3]=f2b(a.w);
  o[4]=f2b(b.x); o[5]=f2b(b.y); o[6]=f2b(b.z); o[7]=f2b(b.w);
  ((u16x8*)dst)[i] = o;
}

// all 4 weight matrices in one launch
__global__ __launch_bounds__(256) void k_cast_w(
    const float* __restrict__ Wq, const float* __restrict__ Wk,
    const float* __restrict__ Wv, const float* __restrict__ Wo,
    u16* __restrict__ wb, u16* __restrict__ wob){
  const int r = blockIdx.x >> 9, bi = blockIdx.x & 511;
  const float* src = (r==0)?Wq:((r==1)?Wk:((r==2)?Wv:Wo));
  u16* dst = (r<3) ? (wb + (size_t)r*1048576) : wob;
  const int i = bi*256 + threadIdx.x;
  const f32x4* s = (const f32x4*)src + (size_t)i*2;
  f32x4 a = s[0], b = s[1];
  u16x8 o;
  o[0]=f2b(a.x); o[1]=f2b(a.y); o[2]=f2b(a.z); o[3]=f2b(a.w);
  o[4]=f2b(b.x); o[5]=f2b(b.y); o[6]=f2b(b.z); o[7]=f2b(b.w);
  ((u16x8*)dst)[i] = o;
}

// ---------------- C = A * B^T  (A:[M,K] bf16, B:[N,K] bf16) ----------------
// XCD-aware bijective block swizzle (nwg % 8 == 0 for both launches).
// MODE 0: N=3072 fused QKV epilogue -> q(*0.125*log2e)/k row-major; V -> vt[(p*64+d)][s]
// MODE 1: f32 epilogue into Cf[M][N]
template<int MODE>
__global__ __launch_bounds__(256) void k_gemm_nt(
    const u16* __restrict__ A, const u16* __restrict__ B,
    float* __restrict__ Cf, u16* __restrict__ Qo, u16* __restrict__ Ko, u16* __restrict__ Vt,
    int K, int N)
{
  __shared__ __attribute__((aligned(16))) u16 As[128*64];
  __shared__ __attribute__((aligned(16))) u16 Bs[128*64];
  const int tid = threadIdx.x, lane = tid & 63, w = tid >> 6;
  const int wr = w >> 1, wc = w & 1;
  // XCD swizzle: chunk tile space per XCD
  const int nwg = gridDim.x * gridDim.y;
  int lin = blockIdx.y * gridDim.x + blockIdx.x;
  lin = (lin & 7) * (nwg >> 3) + (lin >> 3);
  const int n0 = (lin % gridDim.x) * 128;
  const int m0 = (lin / gridDim.x) * 128;
  const int l15 = lane & 15, lg = lane >> 4;
  f32x4 acc[4][4] = {};
  const int lr = lane >> 3, lc = (lane & 7)*8;
  const u16* ag = A + (size_t)(m0 + w*32 + lr)*K + lc;
  const u16* bg = B + (size_t)(n0 + w*32 + lr)*K + lc;
  u16* asl = &As[(w*32)*64];
  u16* bsl = &Bs[(w*32)*64];
  for (int k0 = 0; k0 < K; k0 += 64){
    __syncthreads();
    #pragma unroll
    for (int c = 0; c < 4; ++c){
      GLD16(ag + (size_t)(c*8)*K + k0, asl + c*512);
      GLD16(bg + (size_t)(c*8)*K + k0, bsl + c*512);
    }
    __syncthreads();
    #pragma unroll
    for (int kk = 0; kk < 2; ++kk){
      const int ko = kk*32 + lg*8;
      bf16x8 af[4], bf[4];
      #pragma unroll
      for (int t=0;t<4;++t) af[t] = *(const bf16x8*)&As[(wr*64 + t*16 + l15)*64 + ko];
      #pragma unroll
      for (int t=0;t<4;++t) bf[t] = *(const bf16x8*)&Bs[(wc*64 + t*16 + l15)*64 + ko];
      #pragma unroll
      for (int i=0;i<4;++i)
        #pragma unroll
        for (int j=0;j<4;++j)
          acc[i][j] = MFMA16(af[i], bf[j], acc[i][j]);
    }
  }
  const int col0 = n0 + wc*64 + l15;
  const int row0 = m0 + wr*64 + lg*4;
  if (MODE==0){
    const int which = n0 >> 10;   // uniform per block
    if (which == 2){
      #pragma unroll
      for (int i=0;i<4;++i){
        const int rr0 = row0 + i*16;
        const int bsel = rr0 >> 11, ss = rr0 & 2047;
        #pragma unroll
        for (int j=0;j<4;++j){
          const int d_loc = (col0 + j*16) & 1023;
          const int hh = d_loc >> 6, dd = d_loc & 63;
          u16x4 pk;
          #pragma unroll
          for (int r=0;r<4;++r) pk[r] = f2b(acc[i][j][r]);
          *(u16x4*)(Vt + ((size_t)((bsel*16 + hh)*64 + dd))*2048 + ss) = pk;
        }
      }
    } else {
      u16* dst = which ? Ko : Qo;
      const float scl = which ? 1.f : 0.125f*1.44269504f;  // fold log2(e) into q
      #pragma unroll
      for (int i=0;i<4;++i)
      #pragma unroll
      for (int j=0;j<4;++j){
        const int cc = (col0 + j*16) & 1023;
        #pragma unroll
        for (int r=0;r<4;++r)
          dst[(size_t)(row0 + i*16 + r)*1024 + cc] = f2b(acc[i][j][r]*scl);
      }
    }
  } else {
    #pragma unroll
    for (int i=0;i<4;++i)
    #pragma unroll
    for (int j=0;j<4;++j){
      const int cc = col0 + j*16;
      #pragma unroll
      for (int r=0;r<4;++r)
        Cf[(size_t)(row0 + i*16 + r)*N + cc] = acc[i][j][r];
    }
  }
}

// ---------------- flash attention, in-block kv-split ----------------
// grid 512, 512 threads: blockIdx = p*16 + qt; p=(b*16+h). 8 waves = 2 kv-groups x
// 4 q-subtiles of 32 rows. Group g covers kv in [g*1024,(g+1)*1024), 16 iters.
// q pre-scaled by 0.125*log2e; softmax in log2 domain.
// Lane: q = lane&31, hi = lane>>5.
// QK^T: S^T = MFMA32(Kfrag,Qfrag); PV: O^T = MFMA32(Vfrag,Pfrag); P built in-reg
// via cvt+permlane32_swap. End: group 1 posts bf16 O^T + (m,l) to LDS; group 0
// merges (flash-decode combine) and stores.
__global__ __launch_bounds__(512) void k_attn(
    const u16* __restrict__ q, const u16* __restrict__ k,
    const u16* __restrict__ vt, u16* __restrict__ o)
{
  __shared__ __attribute__((aligned(16))) char KVb[65536]; // [g][buf][K 8KB|V 8KB]
  const int tid = threadIdx.x, lane = tid & 63;
  const int wl = (tid >> 6) & 3, wg = tid >> 8;
  const int p = blockIdx.x >> 4, qt = blockIdx.x & 15;
  const int b = p >> 4, h = p & 15;
  const int l31 = lane & 31, hi = lane >> 5;
  const int qrow = b*2048 + qt*128 + wl*32 + l31;
  const int swz = (l31 & 7) << 4;
  // Q fragments (B operand): col=q (lane l31), k-dim = d = kk*16 + hi*8 + j
  bf16x8 qa[4];
  #pragma unroll
  for (int kk=0;kk<4;++kk)
    qa[kk] = *(const bf16x8*)(q + (size_t)qrow*1024 + h*64 + kk*16 + hi*8);
  // staging: per-wave slot; global source pre-swizzled so LDS dest stays linear
  const char* kgl[2]; const char* vgl[2];
  #pragma unroll
  for (int i=0;i<2;++i){
    const int s = wl*2048 + i*1024 + lane*16;
    const int row = s >> 7;
    const int cb = (s & 127) ^ ((row & 7) << 4);
    kgl[i] = (const char*)k  + ((size_t)(b*2048 + wg*1024 + row))*2048 + h*128 + cb; // + it*64*2048
    vgl[i] = (const char*)vt + ((size_t)(p*64 + row))*4096 + wg*2048 + cb;           // + it*64*2
  }
  const int gbase = wg*32768;
  f32x16 oacc[2] = {};
  float mrow = -1e30f, lrow = 0.f;
  #pragma unroll
  for (int i=0;i<2;++i){
    GLD16(kgl[i], KVb + gbase + wl*2048 + i*1024);
    GLD16(vgl[i], KVb + gbase + 8192 + wl*2048 + i*1024);
  }
  for (int it = 0; it < 16; ++it){
    __syncthreads();   // drains gload_lds + aligns waves
    if (it < 15){
      const size_t nkv = (size_t)(it+1)*64;
      const int nb = gbase + (((it+1)&1)<<14);
      #pragma unroll
      for (int i=0;i<2;++i){
        GLD16(kgl[i] + nkv*2048, KVb + nb + wl*2048 + i*1024);
        GLD16(vgl[i] + nkv*2,    KVb + nb + 8192 + wl*2048 + i*1024);
      }
    }
    const char* Kb = KVb + gbase + ((it&1)<<14);
    const char* Vb = Kb + 8192;
    // QK^T: two 32x32 tiles over kv, K=64 in 4 slices
    f32x16 sacc[2] = {};
    __builtin_amdgcn_s_setprio(1);
    #pragma unroll
    for (int t32=0;t32<2;++t32){
      const int row = t32*32 + l31;
      #pragma unroll
      for (int kk=0;kk<4;++kk){
        bf16x8 kf = *(const bf16x8*)(Kb + row*128 + ((kk*32 + hi*16) ^ swz));
        sacc[t32] = MFMA32(kf, qa[kk], sacc[t32]);
      }
    }
    __builtin_amdgcn_s_setprio(0);
    // online softmax (log2 domain), row q = l31; partner lane^32 holds the
    // complementary kv interleave of the same row.
    float mx = sacc[0][0];
    #pragma unroll
    for (int t32=0;t32<2;++t32)
      #pragma unroll
      for (int i=0;i<16;++i) mx = fmaxf(mx, sacc[t32][i]);
    mx = fmaxf(mx, __shfl_xor(mx, 32));
    if (!__all(mx <= mrow + 8.f)){       // defer-max
      const float mnew = fmaxf(mrow, mx);
      const float scl = exp2fast(mrow - mnew);
      mrow = mnew; lrow *= scl;
      #pragma unroll
      for (int dt=0;dt<2;++dt)
        #pragma unroll
        for (int i=0;i<16;++i) oacc[dt][i] *= scl;
    }
    float rsum = 0.f;
    #pragma unroll
    for (int t32=0;t32<2;++t32)
      #pragma unroll
      for (int i=0;i<16;++i){
        const float e = exp2fast(sacc[t32][i] - mrow);
        sacc[t32][i] = e; rsum += e;
      }
    rsum += __shfl_xor(rsum, 32);
    lrow += rsum;
    // pack P to bf16 pairs
    u32 pk[2][8];
    #pragma unroll
    for (int t32=0;t32<2;++t32)
      #pragma unroll
      for (int u=0;u<8;++u){
        const int idx = (u>>1)*4 + (u&1)*2;
        const u32 lo = b2u((__bf16)sacc[t32][idx]);
        const u32 hh = b2u((__bf16)sacc[t32][idx+1]);
        pk[t32][u] = lo | (hh << 16);
      }
    // PV B-frags via permlane32_swap
    bf16x8 pb[4];
    #pragma unroll
    for (int op=0;op<4;++op){
      const int t32 = op>>1, base = (op&1)*4;
      u32 w0,w1,w2,w3;
      plswap(pk[t32][base+0], pk[t32][base+2], w0, w2, hi);
      plswap(pk[t32][base+1], pk[t32][base+3], w1, w3, hi);
      union { u32 u[4]; bf16x8 v; } cc;
      cc.u[0]=w0; cc.u[1]=w1; cc.u[2]=w2; cc.u[3]=w3;
      pb[op] = cc.v;
    }
    // PV: O^T[d][q]
    __builtin_amdgcn_s_setprio(1);
    #pragma unroll
    for (int dt=0;dt<2;++dt){
      const int row = dt*32 + l31;
      #pragma unroll
      for (int op=0;op<4;++op){
        bf16x8 vf = *(const bf16x8*)(Vb + row*128 + ((op*32 + hi*16) ^ swz));
        oacc[dt] = MFMA32(vf, pb[op], oacc[dt]);
      }
    }
    __builtin_amdgcn_s_setprio(0);
  }
  // ---- merge the two kv-halves via LDS (reuses group-1 KV region) ----
  __syncthreads();
  char* OB = KVb + 32768;            // 16KB bf16 O^T from group 1
  char* MLB = KVb + 49152;           // 1KB (m,l) pairs
  if (wg == 1){
    #pragma unroll
    for (int dt=0;dt<2;++dt)
    #pragma unroll
    for (int rg=0;rg<4;++rg)
    #pragma unroll
    for (int hf=0;hf<2;++hf){
      const int r0 = rg*4 + hf*2;
      const u32 lo = b2u((__bf16)oacc[dt][r0]);
      const u32 hh = b2u((__bf16)oacc[dt][r0+1]);
      const int j = dt*8 + rg*2 + hf;
      *(u32*)(OB + wl*4096 + j*256 + lane*4) = lo | (hh << 16);
    }
    if (hi == 0)
      *(float2*)(MLB + (wl*32 + l31)*8) = make_float2(mrow, lrow);
  }
  __syncthreads();
  if (wg == 0){
    const float2 ml1 = *(const float2*)(MLB + (wl*32 + l31)*8);
    const float m  = fmaxf(mrow, ml1.x);
    const float a0 = exp2fast(mrow - m), a1 = exp2fast(ml1.x - m);
    const float linv = 1.f / (lrow*a0 + ml1.y*a1);
    const float s0 = a0*linv, s1 = a1*linv;
    u16* orow = o + (size_t)qrow*1024 + h*64;
    #pragma unroll
    for (int dt=0;dt<2;++dt)
    #pragma unroll
    for (int rg=0;rg<4;++rg)
    #pragma unroll
    for (int hf=0;hf<2;++hf){
      const int r0 = rg*4 + hf*2;
      const int j = dt*8 + rg*2 + hf;
      const u32 pu = *(const u32*)(OB + wl*4096 + j*256 + lane*4);
      const float p0 = __uint_as_float(pu << 16);
      const float p1 = __uint_as_float(pu & 0xFFFF0000u);
      const float v0 = oacc[dt][r0]  *s0 + p0*s1;
      const float v1 = oacc[dt][r0+1]*s0 + p1*s1;
      *(u32*)(orow + dt*32 + rg*8 + hi*4 + hf*2) = (u32)b2u((__bf16)v0) | ((u32)b2u((__bf16)v1) << 16);
    }
  }
}

// ---------------- fused tail: LN1(x+attn) -> quantum FFN -> +res -> LN2 ----------------
__global__ __launch_bounds__(256) void k_tail(
    const float* __restrict__ x, const float* __restrict__ attn,
    const float* __restrict__ g1, const float* __restrict__ b1,
    const float* __restrict__ Win, const float* __restrict__ b_in,
    const float* __restrict__ Wout, const float* __restrict__ b_out,
    const float* __restrict__ ry,
    const float* __restrict__ g2, const float* __restrict__ b2,
    float* __restrict__ out)
{
  const int tid = threadIdx.x, lane = tid & 63, w = tid >> 6;
  const int t = blockIdx.x*4 + w;
  const size_t base = (size_t)t*1024;
  f32x4 yv[4];
  float s1 = 0.f, s2 = 0.f;
  #pragma unroll
  for (int c=0;c<4;++c){
    const int idx = c*256 + lane*4;
    f32x4 xv = *(const f32x4*)(x + base + idx);
    f32x4 av = *(const f32x4*)(attn + base + idx);
    f32x4 y = xv + av;
    yv[c] = y;
    s1 += y.x + y.y + y.z + y.w;
    s2 += y.x*y.x + y.y*y.y + y.z*y.z + y.w*y.w;
  }
  #pragma unroll
  for (int off=32; off; off>>=1){ s1 += __shfl_xor(s1, off); s2 += __shfl_xor(s2, off); }
  {
    const float mu = s1*(1.f/1024.f);
    const float rinv = rsqrtf(s2*(1.f/1024.f) - mu*mu + 1e-5f);
    #pragma unroll
    for (int c=0;c<4;++c){
      const int idx = c*256 + lane*4;
      f32x4 gv = *(const f32x4*)(g1 + idx);
      f32x4 bv = *(const f32x4*)(b1 + idx);
      f32x4 y = yv[c];
      y.x = (y.x-mu)*rinv*gv.x + bv.x;
      y.y = (y.y-mu)*rinv*gv.y + bv.y;
      y.z = (y.z-mu)*rinv*gv.z + bv.z;
      y.w = (y.w-mu)*rinv*gv.w + bv.w;
      yv[c] = y;
    }
  }
  float ang[8];
  #pragma unroll
  for (int qq=0; qq<8; ++qq){
    float acc = 0.f;
    #pragma unroll
    for (int c=0;c<4;++c){
      f32x4 wv = *(const f32x4*)(Win + qq*1024 + c*256 + lane*4);
      acc += wv.x*yv[c].x + wv.y*yv[c].y + wv.z*yv[c].z + wv.w*yv[c].w;
    }
    ang[qq] = acc;
  }
  #pragma unroll
  for (int off=32; off; off>>=1)
    #pragma unroll
    for (int qq=0; qq<8; ++qq) ang[qq] += __shfl_xor(ang[qq], off);
  #pragma unroll
  for (int qq=0; qq<8; ++qq) ang[qq] += b_in[qq];
  float vr[4], vi[4];
  #pragma unroll
  for (int r=0;r<4;++r){ vr[r]=0.f; vi[r]=0.f; }
  if (lane==0) vr[0] = 1.f;
  #pragma unroll
  for (int wi=0; wi<8; ++wi){       // RX(ang)
    float s, c; __sincosf(ang[wi]*0.5f, &s, &c);
    const int pbit = 7 - wi;
    if (pbit >= 6){
      const int rp = 1 << (pbit-6);
      #pragma unroll
      for (int r=0;r<4;++r) if (!(r & rp)){
        const int r2 = r | rp;
        float ar=vr[r], ai=vi[r], br=vr[r2], bi=vi[r2];
        vr[r]  = c*ar + s*bi;  vi[r]  = c*ai - s*br;
        vr[r2] = c*br + s*ai;  vi[r2] = c*bi - s*ar;
      }
    } else {
      const int msk = 1 << pbit;
      #pragma unroll
      for (int r=0;r<4;++r){
        float orr = __shfl_xor(vr[r], msk);
        float oii = __shfl_xor(vi[r], msk);
        float nr = c*vr[r] + s*oii;
        float ni = c*vi[r] - s*orr;
        vr[r]=nr; vi[r]=ni;
      }
    }
  }
  #pragma unroll
  for (int wi=0; wi<8; ++wi){       // RY(ry)
    float s, c; __sincosf(ry[wi]*0.5f, &s, &c);
    const int pbit = 7 - wi;
    if (pbit >= 6){
      const int rp = 1 << (pbit-6);
      #pragma unroll
      for (int r=0;r<4;++r) if (!(r & rp)){
        const int r2 = r | rp;
        float ar=vr[r], ai=vi[r], br=vr[r2], bi=vi[r2];
        vr[r]  = c*ar - s*br;  vi[r]  = c*ai - s*bi;
        vr[r2] = s*ar + c*br;  vi[r2] = s*ai + c*bi;
      }
    } else {
      const int msk = 1 << pbit;
      const float sg = (lane & msk) ? s : -s;
      #pragma unroll
      for (int r=0;r<4;++r){
        float orr = __shfl_xor(vr[r], msk);
        float oii = __shfl_xor(vi[r], msk);
        float nr = c*vr[r] + sg*orr;
        float ni = c*vi[r] + sg*oii;
        vr[r]=nr; vi[r]=ni;
      }
    }
  }
  { float tr=vr[2]; vr[2]=vr[3]; vr[3]=tr; float ti=vi[2]; vi[2]=vi[3]; vi[3]=ti; }
  vr[1]=__shfl_xor(vr[1],32); vi[1]=__shfl_xor(vi[1],32);
  vr[3]=__shfl_xor(vr[3],32); vi[3]=__shfl_xor(vi[3],32);
  #pragma unroll
  for (int cn=2; cn<7; ++cn){
    const int pc = 7-cn, pt = pc-1;
    const bool ctl = (lane >> pc) & 1;
    #pragma unroll
    for (int r=0;r<4;++r){
      float tr = __shfl_xor(vr[r], 1<<pt);
      float ti = __shfl_xor(vi[r], 1<<pt);
      if (ctl){ vr[r]=tr; vi[r]=ti; }
    }
  }
  float pr[4];
  #pragma unroll
  for (int r=0;r<4;++r) pr[r] = vr[r]*vr[r] + vi[r]*vi[r];
  float e[8];
  e[0] = (pr[0]+pr[1]) - (pr[2]+pr[3]);
  e[1] = (pr[0]+pr[2]) - (pr[1]+pr[3]);
  const float tot = pr[0]+pr[1]+pr[2]+pr[3];
  #pragma unroll
  for (int wi=2; wi<8; ++wi){
    const int pbit = 7-wi;
    e[wi] = ((lane >> pbit) & 1) ? -tot : tot;
  }
  #pragma unroll
  for (int off=1; off<64; off<<=1)
    #pragma unroll
    for (int i=0;i<8;++i) e[i] += __shfl_xor(e[i], off);
  float yy[4][4];
  s1 = 0.f; s2 = 0.f;
  #pragma unroll
  for (int c=0;c<4;++c){
    const float x1a[4] = {yv[c].x, yv[c].y, yv[c].z, yv[c].w};
    #pragma unroll
    for (int j=0;j<4;++j){
      const int d = c*256 + lane*4 + j;
      f32x4 w0 = *(const f32x4*)(Wout + (size_t)d*8);
      f32x4 w1 = *(const f32x4*)(Wout + (size_t)d*8 + 4);
      float acc = b_out[d];
      acc += w0.x*e[0] + w0.y*e[1] + w0.z*e[2] + w0.w*e[3];
      acc += w1.x*e[4] + w1.y*e[5] + w1.z*e[6] + w1.w*e[7];
      const float y = x1a[j] + fmaxf(acc, 0.f);
      yy[c][j] = y;
      s1 += y; s2 += y*y;
    }
  }
  #pragma unroll
  for (int off=32; off; off>>=1){ s1 += __shfl_xor(s1, off); s2 += __shfl_xor(s2, off); }
  const float mu = s1*(1.f/1024.f);
  const float rinv = rsqrtf(s2*(1.f/1024.f) - mu*mu + 1e-5f);
  #pragma unroll
  for (int c=0;c<4;++c){
    const int idx = c*256 + lane*4;
    f32x4 gv = *(const f32x4*)(g2 + idx);
    f32x4 bv = *(const f32x4*)(b2 + idx);
    f32x4 ov;
    ov.x = (yy[c][0]-mu)*rinv*gv.x + bv.x;
    ov.y = (yy[c][1]-mu)*rinv*gv.y + bv.y;
    ov.z = (yy[c][2]-mu)*rinv*gv.z + bv.z;
    ov.w = (yy[c][3]-mu)*rinv*gv.w + bv.w;
    *(f32x4*)(out + base + idx) = ov;
  }
}

extern "C" void kernel_launch(void* const* d_in, const int* in_sizes, int n_in,
                              void* d_out, int out_size, void* d_ws, size_t ws_size,
                              hipStream_t stream)
{
  const float* x    = (const float*)d_in[0];
  const float* Wq   = (const float*)d_in[1];
  const float* Wk   = (const float*)d_in[2];
  const float* Wv   = (const float*)d_in[3];
  const float* Wo   = (const float*)d_in[4];
  const float* g1   = (const float*)d_in[5];
  const float* b1   = (const float*)d_in[6];
  const float* g2   = (const float*)d_in[7];
  const float* b2   = (const float*)d_in[8];
  const float* Win  = (const float*)d_in[9];
  const float* b_in = (const float*)d_in[10];
  const float* Wout = (const float*)d_in[11];
  const float* b_out= (const float*)d_in[12];
  const float* ry   = (const float*)d_in[13];
  float* out = (float*)d_out;
  char* ws = (char*)d_ws;
  const size_t MB = 1024u*1024u;
  u16* xb  = (u16*)(ws + 0*MB);
  u16* wb  = (u16*)(ws + 8*MB);
  u16* wob = (u16*)(ws + 14*MB);
  u16* qb  = (u16*)(ws + 16*MB);
  u16* kb  = (u16*)(ws + 24*MB);
  u16* vtb = (u16*)(ws + 32*MB);
  u16* ob  = (u16*)(ws + 40*MB);
  float* attn_out = (float*)(ws + 48*MB);

  k_cast<<<2048, 256, 0, stream>>>(x, xb);
  k_cast_w<<<2048, 256, 0, stream>>>(Wq, Wk, Wv, Wo, wb, wob);
  k_gemm_nt<0><<<dim3(24,32), 256, 0, stream>>>(xb, wb, nullptr, qb, kb, vtb, 1024, 3072);
  k_attn<<<512, 512, 0, stream>>>(qb, kb, vtb, ob);
  k_gemm_nt<1><<<dim3(8,32), 256, 0, stream>>>(ob, wob, attn_out, nullptr, nullptr, nullptr, 1024, 1024);
  k_tail<<<1024, 256, 0, stream>>>(x, attn_out, g1, b1, Win, b_in, Wout, b_out, ry, g2, b2, out);
}